// Round 14
// baseline (2114.515 us; speedup 1.0000x reference)
//
#include <hip/hip_runtime.h>
#include <cstdio>

using bf8 = __attribute__((ext_vector_type(8))) short;   // 8 bf16 in 4 VGPRs
using f4v = __attribute__((ext_vector_type(4))) float;   // MFMA accum
typedef unsigned short u16;
typedef unsigned int u32;

#define DEV __device__ __forceinline__

DEV float bf2f(u16 u){ return __uint_as_float(((u32)u) << 16); }
DEV u16 f2bf(float f){ u32 u = __float_as_uint(f); return (u16)((u + 0x7fffu + ((u >> 16) & 1u)) >> 16); }
DEV float sigm(float v){ return 1.f / (1.f + __expf(-v)); }

constexpr int P5 = 5, NN = 30000, MM = 50000, NE = 25, BB = 256;
constexpr int KC = 96;            // K chunk staged per round (tgemm)
constexpr int RS = KC * 2 + 16;   // 208 B LDS row stride (tgemm)
constexpr int RSA = 272;          // 256+16 B row stride (full-K tiles)
constexpr int NSEG = 10, SEG = MM / NSEG;   // 5000 edges per segment

// ---------------- prep kernels ----------------
__global__ void temb_k(const float* ts, const float* w1, const float* b1,
                       const float* w2, const float* b2, float* temb){
  int i = blockIdx.x * blockDim.x + threadIdx.x;
  if (i >= BB) return;
  float t = ts[i]; float z[5];
#pragma unroll
  for (int j = 0; j < 5; ++j){ float u = t * w1[j] + b1[j]; z[j] = u * sigm(u); }
#pragma unroll
  for (int j2 = 0; j2 < 5; ++j2){
    float s = b2[j2];
#pragma unroll
    for (int j = 0; j < 5; ++j) s += z[j] * w2[j * 5 + j2];
    temb[i * 5 + j2] = s;
  }
}

// element-parallel transpose: Wt[b][f][k] = W[b][k][f] (bf16, zero-padded), coalesced writes
__global__ void wtransE_k(const float* __restrict__ W, u16* __restrict__ Wt,
                          int Kreal, int Kpad, int Nreal, int Nalloc, int total){
  int idx = blockIdx.x * blockDim.x + threadIdx.x;
  if (idx >= total) return;
  int k = idx % Kpad;
  int t2 = idx / Kpad;
  int f = t2 % Nalloc;
  int b = t2 / Nalloc;
  float v = (k < Kreal && f < Nreal) ? W[((size_t)b * Kreal + k) * Nreal + f] : 0.f;
  Wt[idx] = f2bf(v);
}

// merged emb+cemb block-diagonal weight
__global__ void embw_k(const float* emb_W, const float* emb_b, const float* cemb_W, const float* cemb_b,
                       u16* Wc, float* bc){
  int b = blockIdx.x, f = threadIdx.x;  // 128 threads
  for (int k = 0; k < 32; ++k){
    float v = 0.f;
    if (f < 64){ if (k < 16) v = emb_W[((size_t)b * 16 + k) * 64 + f]; }
    else       { if (k >= 16) v = cemb_W[((size_t)b * 16 + (k - 16)) * 64 + (f - 64)]; }
    Wc[((size_t)b * 128 + f) * 32 + k] = f2bf(v);
  }
  bc[b * 128 + f] = (f < 64) ? emb_b[b * 64 + f] : cemb_b[b * 64 + (f - 64)];
}

// element-parallel gat W transpose: gWt[le][f][h] = W[le][h][f]
__global__ void gwtT_k(const float* __restrict__ gW, u16* __restrict__ gWt){
  int idx = blockIdx.x * blockDim.x + threadIdx.x;
  if (idx >= 75 * 128 * 128) return;
  int h = idx & 127, f = (idx >> 7) & 127, le = idx >> 14;
  gWt[idx] = f2bf(gW[(size_t)le * 16384 + h * 128 + f]);
}

// per (l,e): ws = W@a_s, wd = W@a_d, eaw = We@ae (reductions only)
__global__ void gatred_k(const float* gW, const float* gas, const float* gad,
                         const float* gWe, const float* gae,
                         float* wswd, float* eaw){
  int le = blockIdx.x; int h = threadIdx.x;
  const float* W = gW + (size_t)le * 16384;
  const float* as_ = gas + le * 128;
  const float* ad_ = gad + le * 128;
  float wsv = 0.f, wdv = 0.f;
  for (int f = 0; f < 128; ++f){
    float w = W[h * 128 + f];
    wsv += w * as_[f]; wdv += w * ad_[f];
  }
  wswd[le * 256 + h] = wsv;
  wswd[le * 256 + 128 + h] = wdv;
  if (h < 4){
    const float* We = gWe + (size_t)le * 512;
    const float* ae = gae + le * 128;
    float s = 0.f;
    for (int f = 0; f < 128; ++f) s += We[h * 128 + f] * ae[f];
    eaw[le * 4 + h] = s;
  }
}

// A = [x(13), latent(3), cond(16)] bf16, 32 cols
__global__ void abuild_k(const float* x, const float* cx, u16* A0){
  int idx = blockIdx.x * blockDim.x + threadIdx.x;
  if (idx >= P5 * NN) return;
  const float* xr = x + (size_t)idx * 13;
  const float* cr = cx + (size_t)idx * 19;
  u16* a0 = A0 + (size_t)idx * 32;
#pragma unroll
  for (int i = 0; i < 13; ++i) a0[i] = f2bf(xr[i]);
#pragma unroll
  for (int i = 0; i < 3; ++i) a0[13 + i] = f2bf(cr[16 + i]);
#pragma unroll
  for (int i = 0; i < 16; ++i) a0[16 + i] = f2bf(cr[i]);
}

// write nt (5 temb values) at col co, zeros to end of pitch (embedding stage only)
__global__ void ntfill_k(u16* buf, int pitch, int co, const int* bidx, const float* temb){
  int idx = blockIdx.x * blockDim.x + threadIdx.x;
  if (idx >= P5 * NN) return;
  int b = bidx[idx];
  u16* r = buf + (size_t)idx * pitch;
#pragma unroll
  for (int j = 0; j < 5; ++j) r[co + j] = f2bf(temb[b * 5 + j]);
  for (int j = co + 5; j < pitch; ++j) r[j] = 0;
}

// ---------------- segmented CSR build ----------------
__global__ __launch_bounds__(1024) void csr_cnt_k(const int* __restrict__ EI, u16* __restrict__ hseg){
  extern __shared__ int cntl[];
  int b = blockIdx.x; int e = b / NSEG, s = b - e * NSEG;
  int tid = threadIdx.x;
  for (int i = tid; i < NN; i += 1024) cntl[i] = 0;
  __syncthreads();
  const int* dstp = EI + (size_t)e * 2 * MM + MM;
  int m0 = s * SEG;
  for (int m = m0 + tid; m < m0 + SEG; m += 1024) atomicAdd(&cntl[dstp[m]], 1);
  __syncthreads();
  u16* hp = hseg + ((size_t)e * NSEG + s) * NN;
  for (int i = tid; i < NN; i += 1024) hp[i] = (u16)cntl[i];
}

__global__ __launch_bounds__(1024) void csr_b1_k(const u16* __restrict__ hseg, int* __restrict__ ctot){
  __shared__ int red[16];
  int e = blockIdx.x / 30, c = blockIdx.x % 30;
  int tid = threadIdx.x, lane = tid & 63;
  int d = c * 1000 + tid;
  int tot = 0;
  if (tid < 1000 && d < NN){
    const u16* hb = hseg + (size_t)e * NSEG * NN + d;
    for (int s = 0; s < NSEG; ++s) tot += hb[(size_t)s * NN];
  }
  int v = tot;
#pragma unroll
  for (int o = 32; o > 0; o >>= 1) v += __shfl_down(v, o, 64);
  if (lane == 0) red[tid >> 6] = v;
  __syncthreads();
  if (tid == 0){
    int u = 0;
#pragma unroll
    for (int i = 0; i < 16; ++i) u += red[i];
    ctot[e * 30 + c] = u;
  }
}

__global__ void csr_b2_k(const int* __restrict__ ctot, int* __restrict__ cbase, int* __restrict__ off){
  int e = blockIdx.x, lane = threadIdx.x;
  int v = (lane < 30) ? ctot[e * 30 + lane] : 0;
  int s = v;
#pragma unroll
  for (int o = 1; o < 32; o <<= 1){ int t = __shfl_up(s, o, 64); if (lane >= o) s += t; }
  if (lane < 30) cbase[e * 30 + lane] = s - v;
  if (lane == 29) off[(size_t)e * (NN + 1) + NN] = s;
}

__global__ __launch_bounds__(1024) void csr_b3_k(const u16* __restrict__ hseg, const int* __restrict__ cbase,
                                                 int* __restrict__ off, u32* __restrict__ bseg){
  __shared__ int wsum[16];
  int e = blockIdx.x / 30, c = blockIdx.x % 30;
  int tid = threadIdx.x, lane = tid & 63, wv = tid >> 6;
  int d = c * 1000 + tid;
  bool ok = (tid < 1000 && d < NN);
  int h[NSEG]; int tot = 0;
  if (ok){
    const u16* hb = hseg + (size_t)e * NSEG * NN + d;
#pragma unroll
    for (int s = 0; s < NSEG; ++s){ h[s] = hb[(size_t)s * NN]; tot += h[s]; }
  } else {
#pragma unroll
    for (int s = 0; s < NSEG; ++s) h[s] = 0;
  }
  int v = tot, s1 = v;
#pragma unroll
  for (int o = 1; o < 64; o <<= 1){ int t = __shfl_up(s1, o, 64); if (lane >= o) s1 += t; }
  if (lane == 63) wsum[wv] = s1;
  __syncthreads();
  if (wv == 0 && lane < 16){
    int t = wsum[lane];
#pragma unroll
    for (int o = 1; o < 16; o <<= 1){ int u = __shfl_up(t, o, 64); if (lane >= o) t += u; }
    wsum[lane] = t;
  }
  __syncthreads();
  int excl = ((wv > 0) ? wsum[wv - 1] : 0) + (s1 - v) + cbase[e * 30 + c];
  if (ok){
    off[(size_t)e * (NN + 1) + d] = excl;
    u32 b = (u32)excl;
    u32* bb = bseg + (size_t)e * NSEG * NN + d;
#pragma unroll
    for (int s = 0; s < NSEG; ++s){ bb[(size_t)s * NN] = b; b += (u32)h[s]; }
  }
}

__global__ __launch_bounds__(1024) void csr_fill_k(const int* __restrict__ EI, const u32* __restrict__ bseg,
                                                   int2* __restrict__ sm){
  extern __shared__ int cntl[];
  int b = blockIdx.x; int e = b / NSEG, s = b - e * NSEG;
  int tid = threadIdx.x;
  const u32* bp = bseg + ((size_t)e * NSEG + s) * NN;
  for (int i = tid; i < NN; i += 1024) cntl[i] = (int)bp[i];
  __syncthreads();
  const int* srcp = EI + (size_t)e * 2 * MM;
  const int* dstp = srcp + MM;
  int m0 = s * SEG;
  for (int m = m0 + tid; m < m0 + SEG; m += 1024){
    int d = dstp[m];
    int pos = atomicAdd(&cntl[d], 1);
    int2 v; v.x = srcp[m]; v.y = m;
    sm[(size_t)e * MM + pos] = v;
  }
}

// gather-based eadot: coalesced write, scattered READ of ea (L2/L3-served)
__global__ void eadot_k(const float* __restrict__ ea, const float* __restrict__ eaw,
                        const int2* __restrict__ sm, float* __restrict__ eadot){
  int idx = blockIdx.x * blockDim.x + threadIdx.x;
  if (idx >= 3 * NE * MM) return;
  int l = idx / (NE * MM);
  int rem = idx - l * NE * MM;
  int e = rem / MM, pos = rem - e * MM;
  int m = sm[(size_t)e * MM + pos].y;
  const float* a4 = ea + ((size_t)e * MM + m) * 4;
  const float* ew = eaw + (size_t)(l * NE + e) * 4;
  eadot[idx] = a4[0] * ew[0] + a4[1] * ew[1] + a4[2] * ew[2] + a4[3] * ew[3];
}

// ---------------- GAT edge kernels ----------------
__global__ __launch_bounds__(256) void dots2_k(const u16* __restrict__ hS, const float* __restrict__ wswd_l,
                                               float* __restrict__ als, float* __restrict__ ald){
  __shared__ u32 hl[64][65];
  __shared__ float wsl[10][129];
  int p = blockIdx.y;
  int n0 = blockIdx.x * 64;
  int tid = threadIdx.x;
  for (int i = tid; i < 10 * 128; i += 256){
    int col = i >> 7, k = i & 127;
    int e = (col < 5) ? (p * 5 + col) : ((col - 5) * 5 + p);
    wsl[col][k] = wswd_l[e * 256 + ((col < 5) ? 0 : 128) + k];
  }
  for (int i = tid; i < 64 * 64; i += 256){
    int r = i >> 6, kp = i & 63;
    int n = n0 + r;
    hl[r][kp] = (n < NN) ? ((const u32*)hS)[((size_t)p * NN + n) * 64 + kp] : 0u;
  }
  __syncthreads();
  int col = tid & 15, rbase = tid >> 4;
  if (col < 10){
#pragma unroll
    for (int pass = 0; pass < 4; ++pass){
      int r = rbase + pass * 16;
      int n = n0 + r;
      if (n >= NN) continue;
      float s = 0.f;
#pragma unroll
      for (int kp = 0; kp < 64; ++kp){
        u32 pr = hl[r][kp];
        s += bf2f((u16)(pr & 0xffffu)) * wsl[col][2 * kp]
           + bf2f((u16)(pr >> 16)) * wsl[col][2 * kp + 1];
      }
      if (col < 5) als[(size_t)(p * 5 + col) * NN + n] = s;
      else         ald[(size_t)((col - 5) * 5 + p) * NN + n] = s;
    }
  }
}

// per (e, dst) CSR-row softmax prep
__global__ __launch_bounds__(256) void aexp_k(const float* __restrict__ als, const float* __restrict__ ald,
                                              const float* __restrict__ eadot_l, const int2* __restrict__ sm,
                                              const int* __restrict__ off, uint2* __restrict__ prec){
  int idx = blockIdx.x * blockDim.x + threadIdx.x;
  if (idx >= NE * NN) return;
  int e = idx / NN;
  int ro = off[(size_t)e + idx], re = off[(size_t)e + idx + 1];  // off[e*(NN+1)+n]
  if (ro >= re) return;
  float av = ald[idx];
  const int2* sc = sm + (size_t)e * MM;
  const float* ed = eadot_l + (size_t)e * MM;
  const float* ale = als + (size_t)e * NN;
  float mx = -3.0e38f;
  for (int j = ro; j < re; ++j){
    float a = ale[sc[j].x] + av + ed[j];
    a = (a >= 0.f) ? a : 0.2f * a;
    mx = fmaxf(mx, a);
  }
  for (int j = ro; j < re; ++j){
    int src = sc[j].x;
    float a = ale[src] + av + ed[j];
    a = (a >= 0.f) ? a : 0.2f * a;
    uint2 pr; pr.x = (u32)src; pr.y = __float_as_uint(__expf(a - mx));
    prec[(size_t)e * MM + j] = pr;
  }
}

// ---------------- FUSED agg + transform (v2): 64-row tiles, 8-chain gather, 3 blocks/CU ----------------
// grid (469, 5=pd). comm[pd][n][:] = max_ps( agg(ps,n) @ W[e] + b[e] ). No agghB intermediate.
__global__ __launch_bounds__(256) void fgat2_k(const u16* __restrict__ hS, const uint2* __restrict__ prec,
                                               const int* __restrict__ off, const u16* __restrict__ gWt_l,
                                               const float* __restrict__ gb_l, u16* __restrict__ comm){
  extern __shared__ __align__(16) char smem[];
  char* As = smem;                    // [64][RSA] agg tile bf16
  char* Bs = smem + 64 * RSA;         // [128][RSA] W tile
  float* Cs = (float*)smem;           // fp32 overlay 64x128 for epilogue
  const int tid = threadIdx.x, l = tid & 63, w = tid >> 6;
  const int pd = blockIdx.y;
  const int r0 = blockIdx.x * 64;
  const int wr = w >> 1, wc = w & 1;
  f4v vmax[2][4];
#pragma unroll 1
  for (int ps = 0; ps < 5; ++ps){
    int e = ps * 5 + pd;
    // stage W (L2-hit after first block) — issued before the gather phase
    const u16* wb = gWt_l + (size_t)e * 16384;
    for (int s = tid; s < 128 * 16; s += 256){
      int r = s >> 4, c = s & 15;
      *(uint4*)(Bs + r * RSA + c * 16) = *(const uint4*)(wb + r * 128 + c * 8);
    }
    // gather-aggregate: wave w owns rows [w*16, w*16+16), 8 interleaved chains x 2 groups
    const uint2* pe = prec + (size_t)e * MM;
    const int* offe = off + (size_t)e * (NN + 1);
    const u32* hb = (const u32*)hS + (size_t)ps * NN * 64 + l;
#pragma unroll 1
    for (int g = 0; g < 2; ++g){
      int rb = w * 16 + g * 8;
      float den[8], s0[8], s1[8];
      int ro[8], ln[8];
      int mx = 0;
#pragma unroll
      for (int q = 0; q < 8; ++q){
        int n = r0 + rb + q;
        den[q] = 0.f; s0[q] = 0.f; s1[q] = 0.f;
        if (n < NN){ ro[q] = offe[n]; ln[q] = offe[n + 1] - ro[q]; }
        else { ro[q] = 0; ln[q] = 0; }
        mx = (ln[q] > mx) ? ln[q] : mx;
      }
      for (int t = 0; t < mx; ++t){
#pragma unroll
        for (int q = 0; q < 8; ++q){
          if (t < ln[q]){
            uint2 pr = pe[ro[q] + t];
            float ex = __uint_as_float(pr.y);
            u32 hv = hb[(size_t)pr.x * 64];
            den[q] += ex;
            s0[q] += ex * bf2f((u16)(hv & 0xffffu));
            s1[q] += ex * bf2f((u16)(hv >> 16));
          }
        }
      }
#pragma unroll
      for (int q = 0; q < 8; ++q){
        float inv = 1.f / (den[q] + 1e-16f);
        u32 o = (u32)f2bf(s0[q] * inv) | ((u32)f2bf(s1[q] * inv) << 16);
        *(u32*)(As + (rb + q) * RSA + l * 4) = o;
      }
    }
    __syncthreads();
    // MFMA 64x128 @ W (identical to tgatmm)
    f4v acc[2][4];
#pragma unroll
    for (int i = 0; i < 2; ++i)
#pragma unroll
      for (int j = 0; j < 4; ++j) acc[i][j] = f4v{0.f, 0.f, 0.f, 0.f};
#pragma unroll
    for (int k0 = 0; k0 < 4; ++k0){
      bf8 af[2], bfr[4];
#pragma unroll
      for (int i = 0; i < 2; ++i)
        af[i] = *(const bf8*)(As + (wr * 32 + i * 16 + (l & 15)) * RSA + k0 * 64 + (l >> 4) * 16);
#pragma unroll
      for (int j = 0; j < 4; ++j)
        bfr[j] = *(const bf8*)(Bs + (wc * 64 + j * 16 + (l & 15)) * RSA + k0 * 64 + (l >> 4) * 16);
#pragma unroll
      for (int i = 0; i < 2; ++i)
#pragma unroll
        for (int j = 0; j < 4; ++j)
          acc[i][j] = __builtin_amdgcn_mfma_f32_16x16x32_bf16(af[i], bfr[j], acc[i][j], 0, 0, 0);
    }
    const float* be = gb_l + e * 128;
#pragma unroll
    for (int i = 0; i < 2; ++i)
#pragma unroll
      for (int j = 0; j < 4; ++j){
        int tcol = wc * 64 + j * 16 + (l & 15);
        float bv = be[tcol];
#pragma unroll
        for (int r = 0; r < 4; ++r){
          float cvv = acc[i][j][r] + bv;
          vmax[i][j][r] = (ps == 0) ? cvv : fmaxf(vmax[i][j][r], cvv);
        }
      }
    __syncthreads();
  }
  // epilogue: vmax -> Cs -> linear store (identical to tgatmm)
#pragma unroll
  for (int i = 0; i < 2; ++i)
#pragma unroll
    for (int j = 0; j < 4; ++j){
      int tcol = wc * 64 + j * 16 + (l & 15);
#pragma unroll
      for (int r = 0; r < 4; ++r){
        int trow = wr * 32 + i * 16 + (l >> 4) * 4 + r;
        Cs[trow * 128 + tcol] = vmax[i][j][r];
      }
    }
  __syncthreads();
  for (int s = tid; s < 64 * 32; s += 256){
    int r = s >> 5, c = s & 31;
    int grow = r0 + r; if (grow >= NN) continue;
    float4 cv = *(const float4*)(Cs + r * 128 + c * 4);
    uint2 ov;
    ov.x = (u32)f2bf(cv.x) | ((u32)f2bf(cv.y) << 16);
    ov.y = (u32)f2bf(cv.z) | ((u32)f2bf(cv.w) << 16);
    *(uint2*)(comm + ((size_t)pd * NN + grow) * 128 + c * 4) = ov;
  }
}

// ---------------- LDS-tiled batched GEMM ----------------
// EPI: 0 none; 1 X*sigmoid(v); 2 lrelu; 4 direct fp32 store (Nreal=13)
template<int NF, int MI, int NJ, int EPI, bool ALRELU>
__global__ __launch_bounds__(256) void tgemm_k(const u16* __restrict__ A, const u16* __restrict__ Wt,
                                               const float* __restrict__ bias, void* __restrict__ out,
                                               const u16* __restrict__ X,
                                               int Kpad, int opitch, int ocol, int xpitch){
  constexpr int Nalloc = NF * 16;
  constexpr int WR = 128 / (MI * 16);
  constexpr int WC = 4 / WR;
  static_assert(WR * WC == 4 && NJ * WC * 16 == Nalloc, "wave tiling");
  extern __shared__ __align__(16) char smem[];
  float* Cs = (float*)smem;
  const int tid = threadIdx.x;
  const int l = tid & 63, w = tid >> 6;
  const int bz = blockIdx.z;
  const int r0 = blockIdx.x * 128;
  const int wr = w / WC, wc = w % WC;
  const size_t Ab = (size_t)bz * NN;

  f4v acc[MI][NJ];
#pragma unroll
  for (int i = 0; i < MI; ++i)
#pragma unroll
    for (int j = 0; j < NJ; ++j) acc[i][j] = f4v{0.f, 0.f, 0.f, 0.f};

  for (int kb = 0; kb < Kpad; kb += KC){
    int kc = Kpad - kb; if (kc > KC) kc = KC;
    int nseg = kc >> 3;
    for (int s = tid; s < 128 * nseg; s += 256){
      int r = s / nseg, c = s - r * nseg;
      int grow = r0 + r; if (grow > NN - 1) grow = NN - 1;
      uint4 v = *(const uint4*)(A + (Ab + grow) * Kpad + kb + c * 8);
      if (ALRELU){
        u32 pr[4] = {v.x, v.y, v.z, v.w};
#pragma unroll
        for (int q = 0; q < 4; ++q){
          float lo = bf2f((u16)(pr[q] & 0xffffu)), hi = bf2f((u16)(pr[q] >> 16));
          lo = lo >= 0.f ? lo : 0.01f * lo; hi = hi >= 0.f ? hi : 0.01f * hi;
          pr[q] = (u32)f2bf(lo) | ((u32)f2bf(hi) << 16);
        }
        v.x = pr[0]; v.y = pr[1]; v.z = pr[2]; v.w = pr[3];
      }
      *(uint4*)(smem + r * RS + c * 16) = v;
    }
    for (int s = tid; s < Nalloc * nseg; s += 256){
      int r = s / nseg, c = s - r * nseg;
      uint4 v = *(const uint4*)(Wt + ((size_t)bz * Nalloc + r) * Kpad + kb + c * 8);
      *(uint4*)(smem + 128 * RS + r * RS + c * 16) = v;
    }
    __syncthreads();
    int KI = kc >> 5;
    for (int k0 = 0; k0 < KI; ++k0){
      bf8 af[MI], bfr[NJ];
#pragma unroll
      for (int i = 0; i < MI; ++i){
        int row = wr * (MI * 16) + i * 16 + (l & 15);
        af[i] = *(const bf8*)(smem + row * RS + k0 * 64 + (l >> 4) * 16);
      }
#pragma unroll
      for (int j = 0; j < NJ; ++j){
        int col = wc * (NJ * 16) + j * 16 + (l & 15);
        bfr[j] = *(const bf8*)(smem + 128 * RS + col * RS + k0 * 64 + (l >> 4) * 16);
      }
#pragma unroll
      for (int i = 0; i < MI; ++i)
#pragma unroll
        for (int j = 0; j < NJ; ++j)
          acc[i][j] = __builtin_amdgcn_mfma_f32_16x16x32_bf16(af[i], bfr[j], acc[i][j], 0, 0, 0);
    }
    __syncthreads();
  }

  if (EPI == 4){
    int col = l & 15;
    if (col < 13){
#pragma unroll
      for (int i = 0; i < MI; ++i){
        float bv = bias[bz * 13 + col];
#pragma unroll
        for (int r = 0; r < 4; ++r){
          int grow = r0 + wr * (MI * 16) + i * 16 + (l >> 4) * 4 + r;
          if (grow < NN)
            ((float*)out)[((size_t)bz * NN + grow) * 13 + col] = acc[i][0][r] + bv;
        }
      }
    }
    return;
  }

#pragma unroll
  for (int i = 0; i < MI; ++i)
#pragma unroll
    for (int j = 0; j < NJ; ++j){
      int tcol = wc * (NJ * 16) + j * 16 + (l & 15);
      float bv = bias[bz * Nalloc + tcol];
#pragma unroll
      for (int r = 0; r < 4; ++r){
        int trow = wr * (MI * 16) + i * 16 + (l >> 4) * 4 + r;
        float v = acc[i][j][r] + bv;
        if (EPI == 2) v = v >= 0.f ? v : 0.01f * v;
        Cs[trow * Nalloc + tcol] = v;
      }
    }
  __syncthreads();
  constexpr int nsc = Nalloc / 4;
  u16* o16 = (u16*)out;
  for (int s = tid; s < 128 * nsc; s += 256){
    int r = s / nsc, c = s - r * nsc;
    int grow = r0 + r; if (grow >= NN) continue;
    float4 cv = *(const float4*)(Cs + r * Nalloc + c * 4);
    float v0 = cv.x, v1 = cv.y, v2 = cv.z, v3 = cv.w;
    if (EPI == 1){
      uint2 xv = *(const uint2*)(X + ((size_t)bz * NN + grow) * xpitch + c * 4);
      float x0 = bf2f((u16)(xv.x & 0xffffu)), x1 = bf2f((u16)(xv.x >> 16));
      float x2 = bf2f((u16)(xv.y & 0xffffu)), x3 = bf2f((u16)(xv.y >> 16));
      v0 = x0 * sigm(v0); v1 = x1 * sigm(v1); v2 = x2 * sigm(v2); v3 = x3 * sigm(v3);
    }
    uint2 ov;
    ov.x = (u32)f2bf(v0) | ((u32)f2bf(v1) << 16);
    ov.y = (u32)f2bf(v2) | ((u32)f2bf(v3) << 16);
    *(uint2*)(o16 + ((size_t)bz * NN + grow) * opitch + ocol + c * 4) = ov;
  }
}

// ---------------- fused xc+cc+ca (+nt), 64-row tiles, 256 threads, 34.8KB LDS ----------------
__global__ __launch_bounds__(256) void fca_k(const u16* __restrict__ hS, const u16* __restrict__ comm,
                                             const u16* __restrict__ wxc_l, const float* __restrict__ bxc_l,
                                             const u16* __restrict__ wcc_l, const float* __restrict__ bcc_l,
                                             const u16* __restrict__ wca_l, const float* __restrict__ bca_l,
                                             const int* __restrict__ bidx, const float* __restrict__ temb,
                                             u16* __restrict__ hL){
  extern __shared__ __align__(16) char smem[];
  char* As = smem;                 // [64][RSA]: hS tile / comm tile / caW chunk / vout
  char* H2 = smem + 64 * RSA;      // [64][RSA]: xcW / ccW / h2 bf16
  const int tid = threadIdx.x, l = tid & 63, wv = tid >> 6;
  const int wr = wv >> 1, wc = wv & 1;
  const int bz = blockIdx.z;
  const int r0 = blockIdx.x * 64;
  const size_t pb = (size_t)bz * NN;

  // ---- phase A: hS @ xcW -> h2[:,0:64] ----
  for (int s = tid; s < 64 * 16; s += 256){
    int r = s >> 4, c = s & 15;
    int grow = r0 + r; if (grow > NN - 1) grow = NN - 1;
    *(uint4*)(As + r * RSA + c * 16) = *(const uint4*)(hS + (pb + grow) * 128 + c * 8);
    *(uint4*)(H2 + r * RSA + c * 16) = *(const uint4*)(wxc_l + (size_t)bz * 8192 + r * 128 + c * 8);
  }
  __syncthreads();
  f4v acc_a[2][2], acc_b[2][2];
#pragma unroll
  for (int i = 0; i < 2; ++i)
#pragma unroll
    for (int j = 0; j < 2; ++j) acc_a[i][j] = f4v{0.f, 0.f, 0.f, 0.f};
#pragma unroll
  for (int k0 = 0; k0 < 4; ++k0){
    bf8 af[2], bfr[2];
#pragma unroll
    for (int i = 0; i < 2; ++i)
      af[i] = *(const bf8*)(As + (wr * 32 + i * 16 + (l & 15)) * RSA + k0 * 64 + (l >> 4) * 16);
#pragma unroll
    for (int j = 0; j < 2; ++j)
      bfr[j] = *(const bf8*)(H2 + (wc * 32 + j * 16 + (l & 15)) * RSA + k0 * 64 + (l >> 4) * 16);
#pragma unroll
    for (int i = 0; i < 2; ++i)
#pragma unroll
      for (int j = 0; j < 2; ++j)
        acc_a[i][j] = __builtin_amdgcn_mfma_f32_16x16x32_bf16(af[i], bfr[j], acc_a[i][j], 0, 0, 0);
  }
  __syncthreads();
  // ---- phase B: lrelu(comm) @ ccW -> h2[:,64:128] ----
  for (int s = tid; s < 64 * 16; s += 256){
    int r = s >> 4, c = s & 15;
    int grow = r0 + r; if (grow > NN - 1) grow = NN - 1;
    uint4 v = *(const uint4*)(comm + (pb + grow) * 128 + c * 8);
    u32 pr[4] = {v.x, v.y, v.z, v.w};
#pragma unroll
    for (int q = 0; q < 4; ++q){
      float lo = bf2f((u16)(pr[q] & 0xffffu)), hi = bf2f((u16)(pr[q] >> 16));
      lo = lo >= 0.f ? lo : 0.01f * lo; hi = hi >= 0.f ? hi : 0.01f * hi;
      pr[q] = (u32)f2bf(lo) | ((u32)f2bf(hi) << 16);
    }
    v.x = pr[0]; v.y = pr[1]; v.z = pr[2]; v.w = pr[3];
    *(uint4*)(As + r * RSA + c * 16) = v;
    *(uint4*)(H2 + r * RSA + c * 16) = *(const uint4*)(wcc_l + (size_t)bz * 8192 + r * 128 + c * 8);
  }
  __syncthreads();
#pragma unroll
  for (int i = 0; i < 2; ++i)
#pragma unroll
    for (int j = 0; j < 2; ++j) acc_b[i][j] = f4v{0.f, 0.f, 0.f, 0.f};
#pragma unroll
  for (int k0 = 0; k0 < 4; ++k0){
    bf8 af[2], bfr[2];
#pragma unroll
    for (int i = 0; i < 2; ++i)
      af[i] = *(const bf8*)(As + (wr * 32 + i * 16 + (l & 15)) * RSA + k0 * 64 + (l >> 4) * 16);
#pragma unroll
    for (int j = 0; j < 2; ++j)
      bfr[j] = *(const bf8*)(H2 + (wc * 32 + j * 16 + (l & 15)) * RSA + k0 * 64 + (l >> 4) * 16);
#pragma unroll
    for (int i = 0; i < 2; ++i)
#pragma unroll
      for (int j = 0; j < 2; ++j)
        acc_b[i][j] = __builtin_amdgcn_mfma_f32_16x16x32_bf16(af[i], bfr[j], acc_b[i][j], 0, 0, 0);
  }
  __syncthreads();
  // ---- phase C: h2 (+bias) -> H2 bf16; stage caW chunk0 -> As ----
#pragma unroll
  for (int i = 0; i < 2; ++i)
#pragma unroll
    for (int j = 0; j < 2; ++j){
      int colL = wc * 32 + j * 16 + (l & 15);
      float bL = bxc_l[bz * 64 + colL];
      float bR = bcc_l[bz * 64 + colL];
#pragma unroll
      for (int r = 0; r < 4; ++r){
        int row = wr * 32 + i * 16 + (l >> 4) * 4 + r;
        *(u16*)(H2 + row * RSA + colL * 2)        = f2bf(acc_a[i][j][r] + bL);
        *(u16*)(H2 + row * RSA + (colL + 64) * 2) = f2bf(acc_b[i][j][r] + bR);
      }
    }
  for (int s = tid; s < 64 * 16; s += 256){
    int r = s >> 4, c = s & 15;
    *(uint4*)(As + r * RSA + c * 16) = *(const uint4*)(wca_l + (size_t)bz * 16384 + r * 128 + c * 8);
  }
  __syncthreads();
  // ---- phase D0: g cols 0..63 ----
  f4v acc_g0[2][2], acc_g1[2][2];
#pragma unroll
  for (int i = 0; i < 2; ++i)
#pragma unroll
    for (int j = 0; j < 2; ++j) acc_g0[i][j] = f4v{0.f, 0.f, 0.f, 0.f};
#pragma unroll
  for (int k0 = 0; k0 < 4; ++k0){
    bf8 af[2], bfr[2];
#pragma unroll
    for (int i = 0; i < 2; ++i)
      af[i] = *(const bf8*)(H2 + (wr * 32 + i * 16 + (l & 15)) * RSA + k0 * 64 + (l >> 4) * 16);
#pragma unroll
    for (int j = 0; j < 2; ++j)
      bfr[j] = *(const bf8*)(As + (wc * 32 + j * 16 + (l & 15)) * RSA + k0 * 64 + (l >> 4) * 16);
#pragma unroll
    for (int i = 0; i < 2; ++i)
#pragma unroll
      for (int j = 0; j < 2; ++j)
        acc_g0[i][j] = __builtin_amdgcn_mfma_f32_16x16x32_bf16(af[i], bfr[j], acc_g0[i][j], 0, 0, 0);
  }
  __syncthreads();
  // ---- stage caW chunk1 -> As; phase D1: g cols 64..127 ----
  for (int s = tid; s < 64 * 16; s += 256){
    int r = s >> 4, c = s & 15;
    *(uint4*)(As + r * RSA + c * 16) = *(const uint4*)(wca_l + (size_t)bz * 16384 + (64 + r) * 128 + c * 8);
  }
  __syncthreads();
#pragma unroll
  for (int i = 0; i < 2; ++i)
#pragma unroll
    for (int j = 0; j < 2; ++j) acc_g1[i][j] = f4v{0.f, 0.f, 0.f, 0.f};
#pragma unroll
  for (int k0 = 0; k0 < 4; ++k0){
    bf8 af[2], bfr[2];
#pragma unroll
    for (int i = 0; i < 2; ++i)
      af[i] = *(const bf8*)(H2 + (wr * 32 + i * 16 + (l & 15)) * RSA + k0 * 64 + (l >> 4) * 16);
#pragma unroll
    for (int j = 0; j < 2; ++j)
      bfr[j] = *(const bf8*)(As + (wc * 32 + j * 16 + (l & 15)) * RSA + k0 * 64 + (l >> 4) * 16);
#pragma unroll
    for (int i = 0; i < 2; ++i)
#pragma unroll
      for (int j = 0; j < 2; ++j)
        acc_g1[i][j] = __builtin_amdgcn_mfma_f32_16x16x32_bf16(af[i], bfr[j], acc_g1[i][j], 0, 0, 0);
  }
  // ---- phase E: gate both halves, write vout -> As, linear store ----
  float vout0[2][2][4], vout1[2][2][4];
#pragma unroll
  for (int i = 0; i < 2; ++i)
#pragma unroll
    for (int j = 0; j < 2; ++j){
      int col0 = wc * 32 + j * 16 + (l & 15);
      float bv0 = bca_l[bz * 128 + col0];
      float bv1 = bca_l[bz * 128 + col0 + 64];
#pragma unroll
      for (int r = 0; r < 4; ++r){
        int row = wr * 32 + i * 16 + (l >> 4) * 4 + r;
        float xg0 = bf2f(*(const u16*)(H2 + row * RSA + col0 * 2));
        float xg1 = bf2f(*(const u16*)(H2 + row * RSA + (col0 + 64) * 2));
        vout0[i][j][r] = xg0 * (1.f + sigm(acc_g0[i][j][r] + bv0));
        vout1[i][j][r] = xg1 * (1.f + sigm(acc_g1[i][j][r] + bv1));
      }
    }
  __syncthreads();
#pragma unroll
  for (int i = 0; i < 2; ++i)
#pragma unroll
    for (int j = 0; j < 2; ++j){
      int col0 = wc * 32 + j * 16 + (l & 15);
#pragma unroll
      for (int r = 0; r < 4; ++r){
        int row = wr * 32 + i * 16 + (l >> 4) * 4 + r;
        *(u16*)(As + row * RSA + col0 * 2)        = f2bf(vout0[i][j][r]);
        *(u16*)(As + row * RSA + (col0 + 64) * 2) = f2bf(vout1[i][j][r]);
      }
    }
  __syncthreads();
  for (int s = tid; s < 64 * 40; s += 256){
    int r = s / 40, c = s - r * 40;
    int grow = r0 + r; if (grow >= NN) continue;
    if (c < 32){
      uint2 v = *(const uint2*)(As + r * RSA + c * 8);
      *(uint2*)(hL + (pb + grow) * 160 + c * 4) = v;
    } else {
      int b = bidx[pb + grow];
      int col0 = c * 4;  // 128..156
      u16 t[4];
#pragma unroll
      for (int q = 0; q < 4; ++q){
        int j = col0 + q - 128;
        t[q] = (j < 5) ? f2bf(temb[b * 5 + j]) : (u16)0;
      }
      uint2 ov;
      ov.x = (u32)t[0] | ((u32)t[1] << 16);
      ov.y = (u32)t[2] | ((u32)t[3] << 16);
      *(uint2*)(hL + (pb + grow) * 160 + col0) = ov;
    }
  }
}

// ---------------- workspace layout ----------------
constexpr size_t ALN(size_t x){ return (x + 255) & ~(size_t)255; }
constexpr size_t SZ_A0   = ALN((size_t)P5 * NN * 32 * 2);
constexpr size_t SZ_H0   = ALN((size_t)P5 * NN * 96 * 2);
constexpr size_t SZ_H128 = ALN((size_t)P5 * NN * 128 * 2);
constexpr size_t SZ_HL   = ALN((size_t)P5 * NN * 160 * 2);
constexpr size_t O_A0 = 0;
constexpr size_t O_H0 = O_A0 + SZ_A0;
constexpr size_t O_HCAT = O_H0 + SZ_H0;
constexpr size_t O_HG = O_HCAT + SZ_H128;         // hg (embedding) / comm (layers)
constexpr size_t O_HS = O_HG + SZ_H128;           // hS live through GAT
constexpr size_t O_HL = O_HS + SZ_H128;
// CSR scratch aliases the front region (only used BEFORE abuild):
constexpr size_t O_HSEG = 0;
constexpr size_t O_BSEG = O_HSEG + ALN((size_t)NE * NSEG * NN * 2);
constexpr size_t O_CTOT = O_BSEG + ALN((size_t)NE * NSEG * NN * 4);
constexpr size_t O_CBASE= O_CTOT + ALN((size_t)NE * 30 * 4);
constexpr size_t O_TEMB = O_HL + SZ_HL;
constexpr size_t O_WSWD = O_TEMB + ALN(256 * 5 * 4);
constexpr size_t O_EAW  = O_WSWD + ALN(75 * 256 * 4);
constexpr size_t O_OFFS = O_EAW + ALN(75 * 4 * 4);
constexpr size_t O_ALS  = O_OFFS + ALN((size_t)NE * (NN + 1) * 4);
constexpr size_t O_ALD  = O_ALS + ALN((size_t)NE * NN * 4);
constexpr size_t O_SM   = O_ALD + ALN((size_t)NE * NN * 4);
constexpr size_t O_EADOT= O_SM + ALN((size_t)NE * MM * 8);
constexpr size_t O_GWT  = O_EADOT + ALN((size_t)3 * NE * MM * 4);
constexpr size_t O_WCMB = O_GWT + ALN((size_t)75 * 16384 * 2);
constexpr size_t O_BCMB = O_WCMB + ALN((size_t)5 * 128 * 32 * 2);
constexpr size_t O_WPA  = O_BCMB + ALN((size_t)5 * 128 * 4);
constexpr size_t O_WPC  = O_WPA + ALN((size_t)5 * 128 * 128 * 2);
constexpr size_t O_WSL0 = O_WPC + ALN((size_t)5 * 64 * 128 * 2);
constexpr size_t O_WSL12= O_WSL0 + ALN((size_t)5 * 128 * 96 * 2);
constexpr size_t O_WSLO = O_WSL12 + ALN((size_t)10 * 128 * 160 * 2);
constexpr size_t O_WXC  = O_WSLO + ALN((size_t)5 * 16 * 160 * 2);
constexpr size_t O_WCC  = O_WXC + ALN((size_t)15 * 64 * 128 * 2);
constexpr size_t O_WCA  = O_WCC + ALN((size_t)15 * 64 * 128 * 2);
constexpr size_t O_PREC = O_WCA + ALN((size_t)15 * 128 * 128 * 2);
constexpr size_t WS_NEED= O_PREC + ALN((size_t)NE * MM * 8);

extern "C" void kernel_launch(void* const* d_in, const int* in_sizes, int n_in,
                              void* d_out, int out_size, void* d_ws, size_t ws_size,
                              hipStream_t stream){
  if (ws_size < WS_NEED){
    fprintf(stderr, "kernel_launch: ws too small: need %zu have %zu\n", WS_NEED, ws_size);
    return;
  }
  const float* x        = (const float*)d_in[0];
  const float* cond_x   = (const float*)d_in[1];
  const float* edge_attr= (const float*)d_in[2];
  const float* timesteps= (const float*)d_in[3];
  const float* te1_W = (const float*)d_in[4];
  const float* te1_b = (const float*)d_in[5];
  const float* te2_W = (const float*)d_in[6];
  const float* te2_b = (const float*)d_in[7];
  const float* emb_W = (const float*)d_in[8];
  const float* emb_b = (const float*)d_in[9];
  const float* cemb_W= (const float*)d_in[10];
  const float* cemb_b= (const float*)d_in[11];
  const float* pa_W  = (const float*)d_in[12];
  const float* pa_b  = (const float*)d_in[13];
  const float* pc_W  = (const float*)d_in[14];
  const float* pc_b  = (const float*)d_in[15];
  const float* sl0_W = (const float*)d_in[16];
  const float* sl0_b = (const float*)d_in[17];
  const float* sl12_W= (const float*)d_in[18];
  const float* sl12_b= (const float*)d_in[19];
  const float* slout_W=(const float*)d_in[20];
  const float* slout_b=(const float*)d_in[21];
  const float* gat_W = (const float*)d_in[22];
  const float* gat_as= (const float*)d_in[23];
  const float* gat_ad= (const float*)d_in[24];
  const float* gat_We= (const float*)d_in[25];
  const float* gat_ae= (const float*)d_in[26];
  const float* gat_b = (const float*)d_in[27];
  const float* xc_W  = (const float*)d_in[28];
  const float* xc_b  = (const float*)d_in[29];
  const float* cc_W  = (const float*)d_in[30];
  const float* cc_b  = (const float*)d_in[31];
  const float* ca_W  = (const float*)d_in[32];
  const float* ca_b  = (const float*)d_in[33];
  const int* batch_idx = (const int*)d_in[34];
  const int* edge_index= (const int*)d_in[35];

  char* ws = (char*)d_ws;
  u16* A0    = (u16*)(ws + O_A0);
  u16* h0buf = (u16*)(ws + O_H0);
  u16* hcat  = (u16*)(ws + O_HCAT);
  u16* hg    = (u16*)(ws + O_HG);
  u16* comm  = (u16*)(ws + O_HG);
  u16* hS    = (u16*)(ws + O_HS);
  u16* hL    = (u16*)(ws + O_HL);
  u16* hseg  = (u16*)(ws + O_HSEG);
  u32* bseg  = (u32*)(ws + O_BSEG);
  int* ctot  = (int*)(ws + O_CTOT);
  int* cbase = (int*)(ws + O_CBASE);
  float* tembp = (float*)(ws + O_TEMB);
  float* wswdp = (float*)(ws + O_WSWD);
  float* eawp  = (float*)(ws + O_EAW);
  int* offs = (int*)(ws + O_OFFS);
  float* alsp = (float*)(ws + O_ALS);
  float* aldp = (float*)(ws + O_ALD);
  int2* smp  = (int2*)(ws + O_SM);
  float* eadotp = (float*)(ws + O_EADOT);
  u16* gwt   = (u16*)(ws + O_GWT);
  u16* wcmb  = (u16*)(ws + O_WCMB);
  float* bcmb= (float*)(ws + O_BCMB);
  u16* wpa   = (u16*)(ws + O_WPA);
  u16* wpc   = (u16*)(ws + O_WPC);
  u16* wsl0  = (u16*)(ws + O_WSL0);
  u16* wsl12 = (u16*)(ws + O_WSL12);
  u16* wslo  = (u16*)(ws + O_WSLO);
  u16* wxc   = (u16*)(ws + O_WXC);
  u16* wcc   = (u16*)(ws + O_WCC);
  u16* wca   = (u16*)(ws + O_WCA);
  uint2* precp = (uint2*)(ws + O_PREC);

  const dim3 B256(256);
  const dim3 TG(235, 1, 5);
  const int GPN = (P5 * NN + 255) / 256;
  const int GEN = (NE * NN + 255) / 256;
  constexpr int LDS_N128 = 65536;
  constexpr int LDS_N64  = 39936;
  constexpr int LDS_SLO  = 29952;
  constexpr int LDS_FGAT = 64 * RSA + 128 * RSA;   // 52224 -> 3 blocks/CU
  constexpr int LDS_FCA  = 64 * RSA * 2;           // 34816
  constexpr int LDS_CSR  = NN * 4;                 // 120000

  // ---- prep (element-parallel) ----
  temb_k<<<1, B256, 0, stream>>>(timesteps, te1_W, te1_b, te2_W, te2_b, tembp);
  embw_k<<<5, 128, 0, stream>>>(emb_W, emb_b, cemb_W, cemb_b, wcmb, bcmb);
  {
    auto WT = [&](const float* W, u16* Wt, int Kr, int Kp, int Nr, int Na, int B){
      int total = B * Na * Kp;
      wtransE_k<<<(total + 255) / 256, B256, 0, stream>>>(W, Wt, Kr, Kp, Nr, Na, total);
    };
    WT(pa_W, wpa, 128, 128, 128, 128, 5);
    WT(pc_W, wpc, 128, 128, 64, 64, 5);
    WT(sl0_W, wsl0, 69, 96, 128, 128, 5);
    WT(sl12_W, wsl12, 133, 160, 128, 128, 10);
    WT(slout_W, wslo, 133, 160, 13, 16, 5);
    WT(xc_W, wxc, 128, 128, 64, 64, 15);
    WT(cc_W, wcc, 128, 128, 64, 64, 15);
    WT(ca_W, wca, 128, 128, 128, 128, 15);
  }
  gwtT_k<<<(75 * 128 * 128 + 255) / 256, B256, 0, stream>>>(gat_W, gwt);
  gatred_k<<<75, 128, 0, stream>>>(gat_W, gat_as, gat_ad, gat_We, gat_ae, wswdp, eawp);

  // ---- segmented CSR build + gather-based eadot ----
  csr_cnt_k<<<NE * NSEG, 1024, LDS_CSR, stream>>>(edge_index, hseg);
  csr_b1_k<<<NE * 30, 1024, 0, stream>>>(hseg, ctot);
  csr_b2_k<<<NE, 64, 0, stream>>>(ctot, cbase, offs);
  csr_b3_k<<<NE * 30, 1024, 0, stream>>>(hseg, cbase, offs, bseg);
  csr_fill_k<<<NE * NSEG, 1024, LDS_CSR, stream>>>(edge_index, bseg, smp);
  eadot_k<<<(3 * NE * MM + 255) / 256, B256, 0, stream>>>(edge_attr, eawp, smp, eadotp);

  // ---- input embedding chain ----
  abuild_k<<<GPN, B256, 0, stream>>>(x, cond_x, A0);
  tgemm_k<8, 4, 4, 0, false><<<TG, B256, LDS_N128, stream>>>(A0, wcmb, bcmb, hcat, nullptr, 32, 128, 0, 0);
  tgemm_k<8, 4, 4, 1, false><<<TG, B256, LDS_N128, stream>>>(hcat, wpa, pa_b, hg, hcat, 128, 128, 0, 128);
  tgemm_k<4, 2, 4, 0, false><<<TG, B256, LDS_N64, stream>>>(hg, wpc, pc_b, h0buf, nullptr, 128, 96, 0, 0);
  ntfill_k<<<GPN, B256, 0, stream>>>(h0buf, 96, 64, batch_idx, tembp);

  // ---- layers ----
  for (int l = 0; l < 3; ++l){
    if (l == 0)
      tgemm_k<8, 4, 4, 2, false><<<TG, B256, LDS_N128, stream>>>(h0buf, wsl0, sl0_b, hS, nullptr, 96, 128, 0, 0);
    else
      tgemm_k<8, 4, 4, 2, false><<<TG, B256, LDS_N128, stream>>>(hL, wsl12 + (size_t)(l - 1) * 5 * 128 * 160,
                                                                 sl12_b + (size_t)(l - 1) * 5 * 128, hS, nullptr,
                                                                 160, 128, 0, 0);
    const float* wswd_l = wswdp + (size_t)l * 25 * 256;
    const u16* gwt_l = gwt + (size_t)l * 25 * 16384;
    const float* gb_l = gat_b + (size_t)l * 25 * 128;
    dots2_k<<<dim3(469, 5), B256, 0, stream>>>(hS, wswd_l, alsp, aldp);
    aexp_k<<<GEN, B256, 0, stream>>>(alsp, aldp, eadotp + (size_t)l * NE * MM, smp, offs, precp);
    fgat2_k<<<dim3(469, 5), B256, LDS_FGAT, stream>>>(hS, precp, offs, gwt_l, gb_l, comm);
    fca_k<<<dim3(469, 1, 5), B256, LDS_FCA, stream>>>(hS, comm,
        wxc + (size_t)l * 5 * 64 * 128, xc_b + (size_t)l * 5 * 64,
        wcc + (size_t)l * 5 * 64 * 128, cc_b + (size_t)l * 5 * 64,
        wca + (size_t)l * 5 * 128 * 128, ca_b + (size_t)l * 5 * 128,
        batch_idx, tembp, hL);
  }

  // ---- output head ----
  tgemm_k<1, 2, 1, 4, false><<<TG, B256, LDS_SLO, stream>>>(hL, wslo, slout_b, d_out, nullptr, 160, 13, 0, 0);
}

// Round 15
// 1777.980 us; speedup vs baseline: 1.1893x; 1.1893x over previous
//
#include <hip/hip_runtime.h>
#include <cstdio>

using bf8 = __attribute__((ext_vector_type(8))) short;   // 8 bf16 in 4 VGPRs
using f4v = __attribute__((ext_vector_type(4))) float;   // MFMA accum
typedef unsigned short u16;
typedef unsigned int u32;

#define DEV __device__ __forceinline__

DEV float bf2f(u16 u){ return __uint_as_float(((u32)u) << 16); }
DEV u16 f2bf(float f){ u32 u = __float_as_uint(f); return (u16)((u + 0x7fffu + ((u >> 16) & 1u)) >> 16); }
DEV float sigm(float v){ return 1.f / (1.f + __expf(-v)); }

constexpr int P5 = 5, NN = 30000, MM = 50000, NE = 25, BB = 256;
constexpr int KC = 96;            // K chunk staged per round (tgemm)
constexpr int RS = KC * 2 + 16;   // 208 B LDS row stride (tgemm)
constexpr int RSA = 272;          // 256+16 B row stride (full-K tiles)
constexpr int NSEG = 10, SEG = MM / NSEG;   // 5000 edges per segment

// ---------------- prep kernels ----------------
__global__ void temb_k(const float* ts, const float* w1, const float* b1,
                       const float* w2, const float* b2, float* temb){
  int i = blockIdx.x * blockDim.x + threadIdx.x;
  if (i >= BB) return;
  float t = ts[i]; float z[5];
#pragma unroll
  for (int j = 0; j < 5; ++j){ float u = t * w1[j] + b1[j]; z[j] = u * sigm(u); }
#pragma unroll
  for (int j2 = 0; j2 < 5; ++j2){
    float s = b2[j2];
#pragma unroll
    for (int j = 0; j < 5; ++j) s += z[j] * w2[j * 5 + j2];
    temb[i * 5 + j2] = s;
  }
}

// element-parallel transpose: Wt[b][f][k] = W[b][k][f] (bf16, zero-padded), coalesced writes
__global__ void wtransE_k(const float* __restrict__ W, u16* __restrict__ Wt,
                          int Kreal, int Kpad, int Nreal, int Nalloc, int total){
  int idx = blockIdx.x * blockDim.x + threadIdx.x;
  if (idx >= total) return;
  int k = idx % Kpad;
  int t2 = idx / Kpad;
  int f = t2 % Nalloc;
  int b = t2 / Nalloc;
  float v = (k < Kreal && f < Nreal) ? W[((size_t)b * Kreal + k) * Nreal + f] : 0.f;
  Wt[idx] = f2bf(v);
}

// merged emb+cemb block-diagonal weight
__global__ void embw_k(const float* emb_W, const float* emb_b, const float* cemb_W, const float* cemb_b,
                       u16* Wc, float* bc){
  int b = blockIdx.x, f = threadIdx.x;  // 128 threads
  for (int k = 0; k < 32; ++k){
    float v = 0.f;
    if (f < 64){ if (k < 16) v = emb_W[((size_t)b * 16 + k) * 64 + f]; }
    else       { if (k >= 16) v = cemb_W[((size_t)b * 16 + (k - 16)) * 64 + (f - 64)]; }
    Wc[((size_t)b * 128 + f) * 32 + k] = f2bf(v);
  }
  bc[b * 128 + f] = (f < 64) ? emb_b[b * 64 + f] : cemb_b[b * 64 + (f - 64)];
}

// element-parallel gat W transpose: gWt[le][f][h] = W[le][h][f]
__global__ void gwtT_k(const float* __restrict__ gW, u16* __restrict__ gWt){
  int idx = blockIdx.x * blockDim.x + threadIdx.x;
  if (idx >= 75 * 128 * 128) return;
  int h = idx & 127, f = (idx >> 7) & 127, le = idx >> 14;
  gWt[idx] = f2bf(gW[(size_t)le * 16384 + h * 128 + f]);
}

// per (l,e): ws = W@a_s, wd = W@a_d, eaw = We@ae (reductions only)
__global__ void gatred_k(const float* gW, const float* gas, const float* gad,
                         const float* gWe, const float* gae,
                         float* wswd, float* eaw){
  int le = blockIdx.x; int h = threadIdx.x;
  const float* W = gW + (size_t)le * 16384;
  const float* as_ = gas + le * 128;
  const float* ad_ = gad + le * 128;
  float wsv = 0.f, wdv = 0.f;
  for (int f = 0; f < 128; ++f){
    float w = W[h * 128 + f];
    wsv += w * as_[f]; wdv += w * ad_[f];
  }
  wswd[le * 256 + h] = wsv;
  wswd[le * 256 + 128 + h] = wdv;
  if (h < 4){
    const float* We = gWe + (size_t)le * 512;
    const float* ae = gae + le * 128;
    float s = 0.f;
    for (int f = 0; f < 128; ++f) s += We[h * 128 + f] * ae[f];
    eaw[le * 4 + h] = s;
  }
}

// A = [x(13), latent(3), cond(16)] bf16, 32 cols
__global__ void abuild_k(const float* x, const float* cx, u16* A0){
  int idx = blockIdx.x * blockDim.x + threadIdx.x;
  if (idx >= P5 * NN) return;
  const float* xr = x + (size_t)idx * 13;
  const float* cr = cx + (size_t)idx * 19;
  u16* a0 = A0 + (size_t)idx * 32;
#pragma unroll
  for (int i = 0; i < 13; ++i) a0[i] = f2bf(xr[i]);
#pragma unroll
  for (int i = 0; i < 3; ++i) a0[13 + i] = f2bf(cr[16 + i]);
#pragma unroll
  for (int i = 0; i < 16; ++i) a0[16 + i] = f2bf(cr[i]);
}

// write nt (5 temb values) at col co, zeros to end of pitch (embedding stage only)
__global__ void ntfill_k(u16* buf, int pitch, int co, const int* bidx, const float* temb){
  int idx = blockIdx.x * blockDim.x + threadIdx.x;
  if (idx >= P5 * NN) return;
  int b = bidx[idx];
  u16* r = buf + (size_t)idx * pitch;
#pragma unroll
  for (int j = 0; j < 5; ++j) r[co + j] = f2bf(temb[b * 5 + j]);
  for (int j = co + 5; j < pitch; ++j) r[j] = 0;
}

// ---------------- segmented CSR build ----------------
__global__ __launch_bounds__(1024) void csr_cnt_k(const int* __restrict__ EI, u16* __restrict__ hseg){
  extern __shared__ int cntl[];
  int b = blockIdx.x; int e = b / NSEG, s = b - e * NSEG;
  int tid = threadIdx.x;
  for (int i = tid; i < NN; i += 1024) cntl[i] = 0;
  __syncthreads();
  const int* dstp = EI + (size_t)e * 2 * MM + MM;
  int m0 = s * SEG;
  for (int m = m0 + tid; m < m0 + SEG; m += 1024) atomicAdd(&cntl[dstp[m]], 1);
  __syncthreads();
  u16* hp = hseg + ((size_t)e * NSEG + s) * NN;
  for (int i = tid; i < NN; i += 1024) hp[i] = (u16)cntl[i];
}

__global__ __launch_bounds__(1024) void csr_b1_k(const u16* __restrict__ hseg, int* __restrict__ ctot){
  __shared__ int red[16];
  int e = blockIdx.x / 30, c = blockIdx.x % 30;
  int tid = threadIdx.x, lane = tid & 63;
  int d = c * 1000 + tid;
  int tot = 0;
  if (tid < 1000 && d < NN){
    const u16* hb = hseg + (size_t)e * NSEG * NN + d;
    for (int s = 0; s < NSEG; ++s) tot += hb[(size_t)s * NN];
  }
  int v = tot;
#pragma unroll
  for (int o = 32; o > 0; o >>= 1) v += __shfl_down(v, o, 64);
  if (lane == 0) red[tid >> 6] = v;
  __syncthreads();
  if (tid == 0){
    int u = 0;
#pragma unroll
    for (int i = 0; i < 16; ++i) u += red[i];
    ctot[e * 30 + c] = u;
  }
}

__global__ void csr_b2_k(const int* __restrict__ ctot, int* __restrict__ cbase, int* __restrict__ off){
  int e = blockIdx.x, lane = threadIdx.x;
  int v = (lane < 30) ? ctot[e * 30 + lane] : 0;
  int s = v;
#pragma unroll
  for (int o = 1; o < 32; o <<= 1){ int t = __shfl_up(s, o, 64); if (lane >= o) s += t; }
  if (lane < 30) cbase[e * 30 + lane] = s - v;
  if (lane == 29) off[(size_t)e * (NN + 1) + NN] = s;
}

__global__ __launch_bounds__(1024) void csr_b3_k(const u16* __restrict__ hseg, const int* __restrict__ cbase,
                                                 int* __restrict__ off, u32* __restrict__ bseg){
  __shared__ int wsum[16];
  int e = blockIdx.x / 30, c = blockIdx.x % 30;
  int tid = threadIdx.x, lane = tid & 63, wv = tid >> 6;
  int d = c * 1000 + tid;
  bool ok = (tid < 1000 && d < NN);
  int h[NSEG]; int tot = 0;
  if (ok){
    const u16* hb = hseg + (size_t)e * NSEG * NN + d;
#pragma unroll
    for (int s = 0; s < NSEG; ++s){ h[s] = hb[(size_t)s * NN]; tot += h[s]; }
  } else {
#pragma unroll
    for (int s = 0; s < NSEG; ++s) h[s] = 0;
  }
  int v = tot, s1 = v;
#pragma unroll
  for (int o = 1; o < 64; o <<= 1){ int t = __shfl_up(s1, o, 64); if (lane >= o) s1 += t; }
  if (lane == 63) wsum[wv] = s1;
  __syncthreads();
  if (wv == 0 && lane < 16){
    int t = wsum[lane];
#pragma unroll
    for (int o = 1; o < 16; o <<= 1){ int u = __shfl_up(t, o, 64); if (lane >= o) t += u; }
    wsum[lane] = t;
  }
  __syncthreads();
  int excl = ((wv > 0) ? wsum[wv - 1] : 0) + (s1 - v) + cbase[e * 30 + c];
  if (ok){
    off[(size_t)e * (NN + 1) + d] = excl;
    u32 b = (u32)excl;
    u32* bb = bseg + (size_t)e * NSEG * NN + d;
#pragma unroll
    for (int s = 0; s < NSEG; ++s){ bb[(size_t)s * NN] = b; b += (u32)h[s]; }
  }
}

__global__ __launch_bounds__(1024) void csr_fill_k(const int* __restrict__ EI, const u32* __restrict__ bseg,
                                                   int2* __restrict__ sm){
  extern __shared__ int cntl[];
  int b = blockIdx.x; int e = b / NSEG, s = b - e * NSEG;
  int tid = threadIdx.x;
  const u32* bp = bseg + ((size_t)e * NSEG + s) * NN;
  for (int i = tid; i < NN; i += 1024) cntl[i] = (int)bp[i];
  __syncthreads();
  const int* srcp = EI + (size_t)e * 2 * MM;
  const int* dstp = srcp + MM;
  int m0 = s * SEG;
  for (int m = m0 + tid; m < m0 + SEG; m += 1024){
    int d = dstp[m];
    int pos = atomicAdd(&cntl[d], 1);
    int2 v; v.x = srcp[m]; v.y = m;
    sm[(size_t)e * MM + pos] = v;
  }
}

// gather-based eadot: coalesced write, scattered READ of ea (L2/L3-served)
__global__ void eadot_k(const float* __restrict__ ea, const float* __restrict__ eaw,
                        const int2* __restrict__ sm, float* __restrict__ eadot){
  int idx = blockIdx.x * blockDim.x + threadIdx.x;
  if (idx >= 3 * NE * MM) return;
  int l = idx / (NE * MM);
  int rem = idx - l * NE * MM;
  int e = rem / MM, pos = rem - e * MM;
  int m = sm[(size_t)e * MM + pos].y;
  const float* a4 = ea + ((size_t)e * MM + m) * 4;
  const float* ew = eaw + (size_t)(l * NE + e) * 4;
  eadot[idx] = a4[0] * ew[0] + a4[1] * ew[1] + a4[2] * ew[2] + a4[3] * ew[3];
}

// ---------------- GAT edge kernels ----------------
__global__ __launch_bounds__(256) void dots2_k(const u16* __restrict__ hS, const float* __restrict__ wswd_l,
                                               float* __restrict__ als, float* __restrict__ ald){
  __shared__ u32 hl[64][65];
  __shared__ float wsl[10][129];
  int p = blockIdx.y;
  int n0 = blockIdx.x * 64;
  int tid = threadIdx.x;
  for (int i = tid; i < 10 * 128; i += 256){
    int col = i >> 7, k = i & 127;
    int e = (col < 5) ? (p * 5 + col) : ((col - 5) * 5 + p);
    wsl[col][k] = wswd_l[e * 256 + ((col < 5) ? 0 : 128) + k];
  }
  for (int i = tid; i < 64 * 64; i += 256){
    int r = i >> 6, kp = i & 63;
    int n = n0 + r;
    hl[r][kp] = (n < NN) ? ((const u32*)hS)[((size_t)p * NN + n) * 64 + kp] : 0u;
  }
  __syncthreads();
  int col = tid & 15, rbase = tid >> 4;
  if (col < 10){
#pragma unroll
    for (int pass = 0; pass < 4; ++pass){
      int r = rbase + pass * 16;
      int n = n0 + r;
      if (n >= NN) continue;
      float s = 0.f;
#pragma unroll
      for (int kp = 0; kp < 64; ++kp){
        u32 pr = hl[r][kp];
        s += bf2f((u16)(pr & 0xffffu)) * wsl[col][2 * kp]
           + bf2f((u16)(pr >> 16)) * wsl[col][2 * kp + 1];
      }
      if (col < 5) als[(size_t)(p * 5 + col) * NN + n] = s;
      else         ald[(size_t)((col - 5) * 5 + p) * NN + n] = s;
    }
  }
}

// per (e, dst) CSR-row softmax prep
__global__ __launch_bounds__(256) void aexp_k(const float* __restrict__ als, const float* __restrict__ ald,
                                              const float* __restrict__ eadot_l, const int2* __restrict__ sm,
                                              const int* __restrict__ off, uint2* __restrict__ prec){
  int idx = blockIdx.x * blockDim.x + threadIdx.x;
  if (idx >= NE * NN) return;
  int e = idx / NN;
  int ro = off[(size_t)e + idx], re = off[(size_t)e + idx + 1];  // off[e*(NN+1)+n]
  if (ro >= re) return;
  float av = ald[idx];
  const int2* sc = sm + (size_t)e * MM;
  const float* ed = eadot_l + (size_t)e * MM;
  const float* ale = als + (size_t)e * NN;
  float mx = -3.0e38f;
  for (int j = ro; j < re; ++j){
    float a = ale[sc[j].x] + av + ed[j];
    a = (a >= 0.f) ? a : 0.2f * a;
    mx = fmaxf(mx, a);
  }
  for (int j = ro; j < re; ++j){
    int src = sc[j].x;
    float a = ale[src] + av + ed[j];
    a = (a >= 0.f) ? a : 0.2f * a;
    uint2 pr; pr.x = (u32)src; pr.y = __float_as_uint(__expf(a - mx));
    prec[(size_t)e * MM + j] = pr;
  }
}

// batched aggregation, 2 interleaved row-chains per wave
__global__ __launch_bounds__(256) void agg3_k(const u16* __restrict__ hS, const uint2* __restrict__ prec,
                                              const int* __restrict__ off, u16* __restrict__ agghB,
                                              int pd0, int npd){
  int l = threadIdx.x & 63, w = threadIdx.x >> 6;
  int n0 = blockIdx.x * 8 + w;
  int n1 = n0 + 4;
  int y = blockIdx.y;
  int ps = y / npd, e = ps * 5 + pd0 + (y - ps * npd);
  const uint2* pe = prec + (size_t)e * MM;
  const int* offe = off + (size_t)e * (NN + 1);
  const u32* hb = (const u32*)hS + (size_t)ps * NN * 64 + l;
  int ro0 = 0, ln0 = 0, ro1 = 0, ln1 = 0;
  if (n0 < NN){ ro0 = offe[n0]; ln0 = offe[n0 + 1] - ro0; }
  if (n1 < NN){ ro1 = offe[n1]; ln1 = offe[n1 + 1] - ro1; }
  float den0 = 0.f, a00 = 0.f, a01 = 0.f;
  float den1 = 0.f, a10 = 0.f, a11 = 0.f;
  int mx = (ln0 > ln1) ? ln0 : ln1;
  for (int t = 0; t < mx; ++t){
    if (t < ln0){
      uint2 pr = pe[ro0 + t];
      float ex = __uint_as_float(pr.y);
      u32 hv = hb[(size_t)pr.x * 64];
      den0 += ex; a00 += ex * bf2f((u16)(hv & 0xffffu)); a01 += ex * bf2f((u16)(hv >> 16));
    }
    if (t < ln1){
      uint2 pr = pe[ro1 + t];
      float ex = __uint_as_float(pr.y);
      u32 hv = hb[(size_t)pr.x * 64];
      den1 += ex; a10 += ex * bf2f((u16)(hv & 0xffffu)); a11 += ex * bf2f((u16)(hv >> 16));
    }
  }
  if (n0 < NN){
    float inv = 1.f / (den0 + 1e-16f);
    ((u32*)agghB)[((size_t)y * NN + n0) * 64 + l] = (u32)f2bf(a00 * inv) | ((u32)f2bf(a01 * inv) << 16);
  }
  if (n1 < NN){
    float inv = 1.f / (den1 + 1e-16f);
    ((u32*)agghB)[((size_t)y * NN + n1) * 64 + l] = (u32)f2bf(a10 * inv) | ((u32)f2bf(a11 * inv) << 16);
  }
}

// ---------------- LDS-tiled batched GEMM ----------------
// EPI: 0 none; 1 X*sigmoid(v); 2 lrelu; 4 direct fp32 store (Nreal=13)
template<int NF, int MI, int NJ, int EPI, bool ALRELU>
__global__ __launch_bounds__(256) void tgemm_k(const u16* __restrict__ A, const u16* __restrict__ Wt,
                                               const float* __restrict__ bias, void* __restrict__ out,
                                               const u16* __restrict__ X,
                                               int Kpad, int opitch, int ocol, int xpitch){
  constexpr int Nalloc = NF * 16;
  constexpr int WR = 128 / (MI * 16);
  constexpr int WC = 4 / WR;
  static_assert(WR * WC == 4 && NJ * WC * 16 == Nalloc, "wave tiling");
  extern __shared__ __align__(16) char smem[];
  float* Cs = (float*)smem;
  const int tid = threadIdx.x;
  const int l = tid & 63, w = tid >> 6;
  const int bz = blockIdx.z;
  const int r0 = blockIdx.x * 128;
  const int wr = w / WC, wc = w % WC;
  const size_t Ab = (size_t)bz * NN;

  f4v acc[MI][NJ];
#pragma unroll
  for (int i = 0; i < MI; ++i)
#pragma unroll
    for (int j = 0; j < NJ; ++j) acc[i][j] = f4v{0.f, 0.f, 0.f, 0.f};

  for (int kb = 0; kb < Kpad; kb += KC){
    int kc = Kpad - kb; if (kc > KC) kc = KC;
    int nseg = kc >> 3;
    for (int s = tid; s < 128 * nseg; s += 256){
      int r = s / nseg, c = s - r * nseg;
      int grow = r0 + r; if (grow > NN - 1) grow = NN - 1;
      uint4 v = *(const uint4*)(A + (Ab + grow) * Kpad + kb + c * 8);
      if (ALRELU){
        u32 pr[4] = {v.x, v.y, v.z, v.w};
#pragma unroll
        for (int q = 0; q < 4; ++q){
          float lo = bf2f((u16)(pr[q] & 0xffffu)), hi = bf2f((u16)(pr[q] >> 16));
          lo = lo >= 0.f ? lo : 0.01f * lo; hi = hi >= 0.f ? hi : 0.01f * hi;
          pr[q] = (u32)f2bf(lo) | ((u32)f2bf(hi) << 16);
        }
        v.x = pr[0]; v.y = pr[1]; v.z = pr[2]; v.w = pr[3];
      }
      *(uint4*)(smem + r * RS + c * 16) = v;
    }
    for (int s = tid; s < Nalloc * nseg; s += 256){
      int r = s / nseg, c = s - r * nseg;
      uint4 v = *(const uint4*)(Wt + ((size_t)bz * Nalloc + r) * Kpad + kb + c * 8);
      *(uint4*)(smem + 128 * RS + r * RS + c * 16) = v;
    }
    __syncthreads();
    int KI = kc >> 5;
    for (int k0 = 0; k0 < KI; ++k0){
      bf8 af[MI], bfr[NJ];
#pragma unroll
      for (int i = 0; i < MI; ++i){
        int row = wr * (MI * 16) + i * 16 + (l & 15);
        af[i] = *(const bf8*)(smem + row * RS + k0 * 64 + (l >> 4) * 16);
      }
#pragma unroll
      for (int j = 0; j < NJ; ++j){
        int col = wc * (NJ * 16) + j * 16 + (l & 15);
        bfr[j] = *(const bf8*)(smem + 128 * RS + col * RS + k0 * 64 + (l >> 4) * 16);
      }
#pragma unroll
      for (int i = 0; i < MI; ++i)
#pragma unroll
        for (int j = 0; j < NJ; ++j)
          acc[i][j] = __builtin_amdgcn_mfma_f32_16x16x32_bf16(af[i], bfr[j], acc[i][j], 0, 0, 0);
    }
    __syncthreads();
  }

  if (EPI == 4){
    int col = l & 15;
    if (col < 13){
#pragma unroll
      for (int i = 0; i < MI; ++i){
        float bv = bias[bz * 13 + col];
#pragma unroll
        for (int r = 0; r < 4; ++r){
          int grow = r0 + wr * (MI * 16) + i * 16 + (l >> 4) * 4 + r;
          if (grow < NN)
            ((float*)out)[((size_t)bz * NN + grow) * 13 + col] = acc[i][0][r] + bv;
        }
      }
    }
    return;
  }

#pragma unroll
  for (int i = 0; i < MI; ++i)
#pragma unroll
    for (int j = 0; j < NJ; ++j){
      int tcol = wc * (NJ * 16) + j * 16 + (l & 15);
      float bv = bias[bz * Nalloc + tcol];
#pragma unroll
      for (int r = 0; r < 4; ++r){
        int trow = wr * (MI * 16) + i * 16 + (l >> 4) * 4 + r;
        float v = acc[i][j][r] + bv;
        if (EPI == 2) v = v >= 0.f ? v : 0.01f * v;
        Cs[trow * Nalloc + tcol] = v;
      }
    }
  __syncthreads();
  constexpr int nsc = Nalloc / 4;
  u16* o16 = (u16*)out;
  for (int s = tid; s < 128 * nsc; s += 256){
    int r = s / nsc, c = s - r * nsc;
    int grow = r0 + r; if (grow >= NN) continue;
    float4 cv = *(const float4*)(Cs + r * Nalloc + c * 4);
    float v0 = cv.x, v1 = cv.y, v2 = cv.z, v3 = cv.w;
    if (EPI == 1){
      uint2 xv = *(const uint2*)(X + ((size_t)bz * NN + grow) * xpitch + c * 4);
      float x0 = bf2f((u16)(xv.x & 0xffffu)), x1 = bf2f((u16)(xv.x >> 16));
      float x2 = bf2f((u16)(xv.y & 0xffffu)), x3 = bf2f((u16)(xv.y >> 16));
      v0 = x0 * sigm(v0); v1 = x1 * sigm(v1); v2 = x2 * sigm(v2); v3 = x3 * sigm(v3);
    }
    uint2 ov;
    ov.x = (u32)f2bf(v0) | ((u32)f2bf(v1) << 16);
    ov.y = (u32)f2bf(v2) | ((u32)f2bf(v3) << 16);
    *(uint2*)(o16 + ((size_t)bz * NN + grow) * opitch + ocol + c * 4) = ov;
  }
}

// ---------------- LDS-tiled GAT transform, 64-row tiles (grid 469 per pd) ----------------
__global__ __launch_bounds__(256) void tgatmm_k(const u16* __restrict__ agghB, const u16* __restrict__ gWt_l,
                                                const float* __restrict__ gb_l, u16* __restrict__ comm,
                                                int pd){
  extern __shared__ __align__(16) char smem[];
  char* As = smem;                    // [64][RSA]
  char* Bs = smem + 64 * RSA;         // [128][RSA]
  float* Cs = (float*)smem;           // fp32 overlay 64x128 for epilogue
  const int tid = threadIdx.x, l = tid & 63, w = tid >> 6;
  const int r0 = blockIdx.x * 64;
  const int wr = w >> 1, wc = w & 1;
  f4v vmax[2][4];
#pragma unroll 1
  for (int ps = 0; ps < 5; ++ps){
    int e = ps * 5 + pd;
    const u16* aggs = agghB + (size_t)ps * NN * 128;
    const u16* wb = gWt_l + (size_t)e * 16384;
    for (int s = tid; s < 64 * 16; s += 256){
      int r = s >> 4, c = s & 15;
      int grow = r0 + r; if (grow > NN - 1) grow = NN - 1;
      *(uint4*)(As + r * RSA + c * 16) = *(const uint4*)(aggs + (size_t)grow * 128 + c * 8);
    }
    for (int s = tid; s < 128 * 16; s += 256){
      int r = s >> 4, c = s & 15;
      *(uint4*)(Bs + r * RSA + c * 16) = *(const uint4*)(wb + r * 128 + c * 8);
    }
    __syncthreads();
    f4v acc[2][4];
#pragma unroll
    for (int i = 0; i < 2; ++i)
#pragma unroll
      for (int j = 0; j < 4; ++j) acc[i][j] = f4v{0.f, 0.f, 0.f, 0.f};
#pragma unroll
    for (int k0 = 0; k0 < 4; ++k0){
      bf8 af[2], bfr[4];
#pragma unroll
      for (int i = 0; i < 2; ++i)
        af[i] = *(const bf8*)(As + (wr * 32 + i * 16 + (l & 15)) * RSA + k0 * 64 + (l >> 4) * 16);
#pragma unroll
      for (int j = 0; j < 4; ++j)
        bfr[j] = *(const bf8*)(Bs + (wc * 64 + j * 16 + (l & 15)) * RSA + k0 * 64 + (l >> 4) * 16);
#pragma unroll
      for (int i = 0; i < 2; ++i)
#pragma unroll
        for (int j = 0; j < 4; ++j)
          acc[i][j] = __builtin_amdgcn_mfma_f32_16x16x32_bf16(af[i], bfr[j], acc[i][j], 0, 0, 0);
    }
    const float* be = gb_l + e * 128;
#pragma unroll
    for (int i = 0; i < 2; ++i)
#pragma unroll
      for (int j = 0; j < 4; ++j){
        int tcol = wc * 64 + j * 16 + (l & 15);
        float bv = be[tcol];
#pragma unroll
        for (int r = 0; r < 4; ++r){
          float cvv = acc[i][j][r] + bv;
          vmax[i][j][r] = (ps == 0) ? cvv : fmaxf(vmax[i][j][r], cvv);
        }
      }
    __syncthreads();
  }
#pragma unroll
  for (int i = 0; i < 2; ++i)
#pragma unroll
    for (int j = 0; j < 4; ++j){
      int tcol = wc * 64 + j * 16 + (l & 15);
#pragma unroll
      for (int r = 0; r < 4; ++r){
        int trow = wr * 32 + i * 16 + (l >> 4) * 4 + r;
        Cs[trow * 128 + tcol] = vmax[i][j][r];
      }
    }
  __syncthreads();
  for (int s = tid; s < 64 * 32; s += 256){
    int r = s >> 5, c = s & 31;
    int grow = r0 + r; if (grow >= NN) continue;
    float4 cv = *(const float4*)(Cs + r * 128 + c * 4);
    uint2 ov;
    ov.x = (u32)f2bf(cv.x) | ((u32)f2bf(cv.y) << 16);
    ov.y = (u32)f2bf(cv.z) | ((u32)f2bf(cv.w) << 16);
    *(uint2*)(comm + ((size_t)pd * NN + grow) * 128 + c * 4) = ov;
  }
}

// ---------------- fused xc+cc+ca (+nt), 64-row tiles, 256 threads, 34.8KB LDS ----------------
__global__ __launch_bounds__(256) void fca_k(const u16* __restrict__ hS, const u16* __restrict__ comm,
                                             const u16* __restrict__ wxc_l, const float* __restrict__ bxc_l,
                                             const u16* __restrict__ wcc_l, const float* __restrict__ bcc_l,
                                             const u16* __restrict__ wca_l, const float* __restrict__ bca_l,
                                             const int* __restrict__ bidx, const float* __restrict__ temb,
                                             u16* __restrict__ hL){
  extern __shared__ __align__(16) char smem[];
  char* As = smem;                 // [64][RSA]: hS tile / comm tile / caW chunk / vout
  char* H2 = smem + 64 * RSA;      // [64][RSA]: xcW / ccW / h2 bf16
  const int tid = threadIdx.x, l = tid & 63, wv = tid >> 6;
  const int wr = wv >> 1, wc = wv & 1;
  const int bz = blockIdx.z;
  const int r0 = blockIdx.x * 64;
  const size_t pb = (size_t)bz * NN;

  // ---- phase A: hS @ xcW -> h2[:,0:64] ----
  for (int s = tid; s < 64 * 16; s += 256){
    int r = s >> 4, c = s & 15;
    int grow = r0 + r; if (grow > NN - 1) grow = NN - 1;
    *(uint4*)(As + r * RSA + c * 16) = *(const uint4*)(hS + (pb + grow) * 128 + c * 8);
    *(uint4*)(H2 + r * RSA + c * 16) = *(const uint4*)(wxc_l + (size_t)bz * 8192 + r * 128 + c * 8);
  }
  __syncthreads();
  f4v acc_a[2][2], acc_b[2][2];
#pragma unroll
  for (int i = 0; i < 2; ++i)
#pragma unroll
    for (int j = 0; j < 2; ++j) acc_a[i][j] = f4v{0.f, 0.f, 0.f, 0.f};
#pragma unroll
  for (int k0 = 0; k0 < 4; ++k0){
    bf8 af[2], bfr[2];
#pragma unroll
    for (int i = 0; i < 2; ++i)
      af[i] = *(const bf8*)(As + (wr * 32 + i * 16 + (l & 15)) * RSA + k0 * 64 + (l >> 4) * 16);
#pragma unroll
    for (int j = 0; j < 2; ++j)
      bfr[j] = *(const bf8*)(H2 + (wc * 32 + j * 16 + (l & 15)) * RSA + k0 * 64 + (l >> 4) * 16);
#pragma unroll
    for (int i = 0; i < 2; ++i)
#pragma unroll
      for (int j = 0; j < 2; ++j)
        acc_a[i][j] = __builtin_amdgcn_mfma_f32_16x16x32_bf16(af[i], bfr[j], acc_a[i][j], 0, 0, 0);
  }
  __syncthreads();
  // ---- phase B: lrelu(comm) @ ccW -> h2[:,64:128] ----
  for (int s = tid; s < 64 * 16; s += 256){
    int r = s >> 4, c = s & 15;
    int grow = r0 + r; if (grow > NN - 1) grow = NN - 1;
    uint4 v = *(const uint4*)(comm + (pb + grow) * 128 + c * 8);
    u32 pr[4] = {v.x, v.y, v.z, v.w};
#pragma unroll
    for (int q = 0; q < 4; ++q){
      float lo = bf2f((u16)(pr[q] & 0xffffu)), hi = bf2f((u16)(pr[q] >> 16));
      lo = lo >= 0.f ? lo : 0.01f * lo; hi = hi >= 0.f ? hi : 0.01f * hi;
      pr[q] = (u32)f2bf(lo) | ((u32)f2bf(hi) << 16);
    }
    v.x = pr[0]; v.y = pr[1]; v.z = pr[2]; v.w = pr[3];
    *(uint4*)(As + r * RSA + c * 16) = v;
    *(uint4*)(H2 + r * RSA + c * 16) = *(const uint4*)(wcc_l + (size_t)bz * 8192 + r * 128 + c * 8);
  }
  __syncthreads();
#pragma unroll
  for (int i = 0; i < 2; ++i)
#pragma unroll
    for (int j = 0; j < 2; ++j) acc_b[i][j] = f4v{0.f, 0.f, 0.f, 0.f};
#pragma unroll
  for (int k0 = 0; k0 < 4; ++k0){
    bf8 af[2], bfr[2];
#pragma unroll
    for (int i = 0; i < 2; ++i)
      af[i] = *(const bf8*)(As + (wr * 32 + i * 16 + (l & 15)) * RSA + k0 * 64 + (l >> 4) * 16);
#pragma unroll
    for (int j = 0; j < 2; ++j)
      bfr[j] = *(const bf8*)(H2 + (wc * 32 + j * 16 + (l & 15)) * RSA + k0 * 64 + (l >> 4) * 16);
#pragma unroll
    for (int i = 0; i < 2; ++i)
#pragma unroll
      for (int j = 0; j < 2; ++j)
        acc_b[i][j] = __builtin_amdgcn_mfma_f32_16x16x32_bf16(af[i], bfr[j], acc_b[i][j], 0, 0, 0);
  }
  __syncthreads();
  // ---- phase C: h2 (+bias) -> H2 bf16; stage caW chunk0 -> As ----
#pragma unroll
  for (int i = 0; i < 2; ++i)
#pragma unroll
    for (int j = 0; j < 2; ++j){
      int colL = wc * 32 + j * 16 + (l & 15);
      float bL = bxc_l[bz * 64 + colL];
      float bR = bcc_l[bz * 64 + colL];
#pragma unroll
      for (int r = 0; r < 4; ++r){
        int row = wr * 32 + i * 16 + (l >> 4) * 4 + r;
        *(u16*)(H2 + row * RSA + colL * 2)        = f2bf(acc_a[i][j][r] + bL);
        *(u16*)(H2 + row * RSA + (colL + 64) * 2) = f2bf(acc_b[i][j][r] + bR);
      }
    }
  for (int s = tid; s < 64 * 16; s += 256){
    int r = s >> 4, c = s & 15;
    *(uint4*)(As + r * RSA + c * 16) = *(const uint4*)(wca_l + (size_t)bz * 16384 + r * 128 + c * 8);
  }
  __syncthreads();
  // ---- phase D0: g cols 0..63 ----
  f4v acc_g0[2][2], acc_g1[2][2];
#pragma unroll
  for (int i = 0; i < 2; ++i)
#pragma unroll
    for (int j = 0; j < 2; ++j) acc_g0[i][j] = f4v{0.f, 0.f, 0.f, 0.f};
#pragma unroll
  for (int k0 = 0; k0 < 4; ++k0){
    bf8 af[2], bfr[2];
#pragma unroll
    for (int i = 0; i < 2; ++i)
      af[i] = *(const bf8*)(H2 + (wr * 32 + i * 16 + (l & 15)) * RSA + k0 * 64 + (l >> 4) * 16);
#pragma unroll
    for (int j = 0; j < 2; ++j)
      bfr[j] = *(const bf8*)(As + (wc * 32 + j * 16 + (l & 15)) * RSA + k0 * 64 + (l >> 4) * 16);
#pragma unroll
    for (int i = 0; i < 2; ++i)
#pragma unroll
      for (int j = 0; j < 2; ++j)
        acc_g0[i][j] = __builtin_amdgcn_mfma_f32_16x16x32_bf16(af[i], bfr[j], acc_g0[i][j], 0, 0, 0);
  }
  __syncthreads();
  // ---- stage caW chunk1 -> As; phase D1: g cols 64..127 ----
  for (int s = tid; s < 64 * 16; s += 256){
    int r = s >> 4, c = s & 15;
    *(uint4*)(As + r * RSA + c * 16) = *(const uint4*)(wca_l + (size_t)bz * 16384 + (64 + r) * 128 + c * 8);
  }
  __syncthreads();
#pragma unroll
  for (int i = 0; i < 2; ++i)
#pragma unroll
    for (int j = 0; j < 2; ++j) acc_g1[i][j] = f4v{0.f, 0.f, 0.f, 0.f};
#pragma unroll
  for (int k0 = 0; k0 < 4; ++k0){
    bf8 af[2], bfr[2];
#pragma unroll
    for (int i = 0; i < 2; ++i)
      af[i] = *(const bf8*)(H2 + (wr * 32 + i * 16 + (l & 15)) * RSA + k0 * 64 + (l >> 4) * 16);
#pragma unroll
    for (int j = 0; j < 2; ++j)
      bfr[j] = *(const bf8*)(As + (wc * 32 + j * 16 + (l & 15)) * RSA + k0 * 64 + (l >> 4) * 16);
#pragma unroll
    for (int i = 0; i < 2; ++i)
#pragma unroll
      for (int j = 0; j < 2; ++j)
        acc_g1[i][j] = __builtin_amdgcn_mfma_f32_16x16x32_bf16(af[i], bfr[j], acc_g1[i][j], 0, 0, 0);
  }
  // ---- phase E: gate both halves, write vout -> As, linear store ----
  float vout0[2][2][4], vout1[2][2][4];
#pragma unroll
  for (int i = 0; i < 2; ++i)
#pragma unroll
    for (int j = 0; j < 2; ++j){
      int col0 = wc * 32 + j * 16 + (l & 15);
      float bv0 = bca_l[bz * 128 + col0];
      float bv1 = bca_l[bz * 128 + col0 + 64];
#pragma unroll
      for (int r = 0; r < 4; ++r){
        int row = wr * 32 + i * 16 + (l >> 4) * 4 + r;
        float xg0 = bf2f(*(const u16*)(H2 + row * RSA + col0 * 2));
        float xg1 = bf2f(*(const u16*)(H2 + row * RSA + (col0 + 64) * 2));
        vout0[i][j][r] = xg0 * (1.f + sigm(acc_g0[i][j][r] + bv0));
        vout1[i][j][r] = xg1 * (1.f + sigm(acc_g1[i][j][r] + bv1));
      }
    }
  __syncthreads();
#pragma unroll
  for (int i = 0; i < 2; ++i)
#pragma unroll
    for (int j = 0; j < 2; ++j){
      int col0 = wc * 32 + j * 16 + (l & 15);
#pragma unroll
      for (int r = 0; r < 4; ++r){
        int row = wr * 32 + i * 16 + (l >> 4) * 4 + r;
        *(u16*)(As + row * RSA + col0 * 2)        = f2bf(vout0[i][j][r]);
        *(u16*)(As + row * RSA + (col0 + 64) * 2) = f2bf(vout1[i][j][r]);
      }
    }
  __syncthreads();
  for (int s = tid; s < 64 * 40; s += 256){
    int r = s / 40, c = s - r * 40;
    int grow = r0 + r; if (grow >= NN) continue;
    if (c < 32){
      uint2 v = *(const uint2*)(As + r * RSA + c * 8);
      *(uint2*)(hL + (pb + grow) * 160 + c * 4) = v;
    } else {
      int b = bidx[pb + grow];
      int col0 = c * 4;  // 128..156
      u16 t[4];
#pragma unroll
      for (int q = 0; q < 4; ++q){
        int j = col0 + q - 128;
        t[q] = (j < 5) ? f2bf(temb[b * 5 + j]) : (u16)0;
      }
      uint2 ov;
      ov.x = (u32)t[0] | ((u32)t[1] << 16);
      ov.y = (u32)t[2] | ((u32)t[3] << 16);
      *(uint2*)(hL + (pb + grow) * 160 + col0) = ov;
    }
  }
}

// ---------------- workspace layout ----------------
constexpr size_t ALN(size_t x){ return (x + 255) & ~(size_t)255; }
constexpr size_t SZ_A0   = ALN((size_t)P5 * NN * 32 * 2);
constexpr size_t SZ_H0   = ALN((size_t)P5 * NN * 96 * 2);
constexpr size_t SZ_H128 = ALN((size_t)P5 * NN * 128 * 2);
constexpr size_t SZ_HL   = ALN((size_t)P5 * NN * 160 * 2);
constexpr size_t O_A0 = 0;
constexpr size_t O_H0 = O_A0 + SZ_A0;
constexpr size_t O_AGG = 0;                       // slab region (A0/h0/hcat dead during GAT)
constexpr size_t O_HCAT = O_H0 + SZ_H0;
constexpr size_t O_HG = O_HCAT + SZ_H128;         // hg (embedding) / comm (layers)
constexpr size_t O_HS = O_HG + SZ_H128;           // hS live through GAT
constexpr size_t O_HL = O_HS + SZ_H128;
// CSR scratch aliases the slab region (only used BEFORE abuild):
constexpr size_t O_HSEG = 0;
constexpr size_t O_BSEG = O_HSEG + ALN((size_t)NE * NSEG * NN * 2);
constexpr size_t O_CTOT = O_BSEG + ALN((size_t)NE * NSEG * NN * 4);
constexpr size_t O_CBASE= O_CTOT + ALN((size_t)NE * 30 * 4);
constexpr size_t O_TEMB = O_HL + SZ_HL;
constexpr size_t O_WSWD = O_TEMB + ALN(256 * 5 * 4);
constexpr size_t O_EAW  = O_WSWD + ALN(75 * 256 * 4);
constexpr size_t O_OFFS = O_EAW + ALN(75 * 4 * 4);
constexpr size_t O_ALS  = O_OFFS + ALN((size_t)NE * (NN + 1) * 4);
constexpr size_t O_ALD  = O_ALS + ALN((size_t)NE * NN * 4);
constexpr size_t O_SM   = O_ALD + ALN((size_t)NE * NN * 4);
constexpr size_t O_EADOT= O_SM + ALN((size_t)NE * MM * 8);
constexpr size_t O_GWT  = O_EADOT + ALN((size_t)3 * NE * MM * 4);
constexpr size_t O_WCMB = O_GWT + ALN((size_t)75 * 16384 * 2);
constexpr size_t O_BCMB = O_WCMB + ALN((size_t)5 * 128 * 32 * 2);
constexpr size_t O_WPA  = O_BCMB + ALN((size_t)5 * 128 * 4);
constexpr size_t O_WPC  = O_WPA + ALN((size_t)5 * 128 * 128 * 2);
constexpr size_t O_WSL0 = O_WPC + ALN((size_t)5 * 64 * 128 * 2);
constexpr size_t O_WSL12= O_WSL0 + ALN((size_t)5 * 128 * 96 * 2);
constexpr size_t O_WSLO = O_WSL12 + ALN((size_t)10 * 128 * 160 * 2);
constexpr size_t O_WXC  = O_WSLO + ALN((size_t)5 * 16 * 160 * 2);
constexpr size_t O_WCC  = O_WXC + ALN((size_t)15 * 64 * 128 * 2);
constexpr size_t O_WCA  = O_WCC + ALN((size_t)15 * 64 * 128 * 2);
constexpr size_t O_PREC = O_WCA + ALN((size_t)15 * 128 * 128 * 2);
constexpr size_t WS_NEED= O_PREC + ALN((size_t)NE * MM * 8);

extern "C" void kernel_launch(void* const* d_in, const int* in_sizes, int n_in,
                              void* d_out, int out_size, void* d_ws, size_t ws_size,
                              hipStream_t stream){
  if (ws_size < WS_NEED){
    fprintf(stderr, "kernel_launch: ws too small: need %zu have %zu\n", WS_NEED, ws_size);
    return;
  }
  const float* x        = (const float*)d_in[0];
  const float* cond_x   = (const float*)d_in[1];
  const float* edge_attr= (const float*)d_in[2];
  const float* timesteps= (const float*)d_in[3];
  const float* te1_W = (const float*)d_in[4];
  const float* te1_b = (const float*)d_in[5];
  const float* te2_W = (const float*)d_in[6];
  const float* te2_b = (const float*)d_in[7];
  const float* emb_W = (const float*)d_in[8];
  const float* emb_b = (const float*)d_in[9];
  const float* cemb_W= (const float*)d_in[10];
  const float* cemb_b= (const float*)d_in[11];
  const float* pa_W  = (const float*)d_in[12];
  const float* pa_b  = (const float*)d_in[13];
  const float* pc_W  = (const float*)d_in[14];
  const float* pc_b  = (const float*)d_in[15];
  const float* sl0_W = (const float*)d_in[16];
  const float* sl0_b = (const float*)d_in[17];
  const float* sl12_W= (const float*)d_in[18];
  const float* sl12_b= (const float*)d_in[19];
  const float* slout_W=(const float*)d_in[20];
  const float* slout_b=(const float*)d_in[21];
  const float* gat_W = (const float*)d_in[22];
  const float* gat_as= (const float*)d_in[23];
  const float* gat_ad= (const float*)d_in[24];
  const float* gat_We= (const float*)d_in[25];
  const float* gat_ae= (const float*)d_in[26];
  const float* gat_b = (const float*)d_in[27];
  const float* xc_W  = (const float*)d_in[28];
  const float* xc_b  = (const float*)d_in[29];
  const float* cc_W  = (const float*)d_in[30];
  const float* cc_b  = (const float*)d_in[31];
  const float* ca_W  = (const float*)d_in[32];
  const float* ca_b  = (const float*)d_in[33];
  const int* batch_idx = (const int*)d_in[34];
  const int* edge_index= (const int*)d_in[35];

  char* ws = (char*)d_ws;
  u16* A0    = (u16*)(ws + O_A0);
  u16* h0buf = (u16*)(ws + O_H0);
  u16* agghB = (u16*)(ws + O_AGG);
  u16* hcat  = (u16*)(ws + O_HCAT);
  u16* hg    = (u16*)(ws + O_HG);
  u16* comm  = (u16*)(ws + O_HG);
  u16* hS    = (u16*)(ws + O_HS);
  u16* hL    = (u16*)(ws + O_HL);
  u16* hseg  = (u16*)(ws + O_HSEG);
  u32* bseg  = (u32*)(ws + O_BSEG);
  int* ctot  = (int*)(ws + O_CTOT);
  int* cbase = (int*)(ws + O_CBASE);
  float* tembp = (float*)(ws + O_TEMB);
  float* wswdp = (float*)(ws + O_WSWD);
  float* eawp  = (float*)(ws + O_EAW);
  int* offs = (int*)(ws + O_OFFS);
  float* alsp = (float*)(ws + O_ALS);
  float* aldp = (float*)(ws + O_ALD);
  int2* smp  = (int2*)(ws + O_SM);
  float* eadotp = (float*)(ws + O_EADOT);
  u16* gwt   = (u16*)(ws + O_GWT);
  u16* wcmb  = (u16*)(ws + O_WCMB);
  float* bcmb= (float*)(ws + O_BCMB);
  u16* wpa   = (u16*)(ws + O_WPA);
  u16* wpc   = (u16*)(ws + O_WPC);
  u16* wsl0  = (u16*)(ws + O_WSL0);
  u16* wsl12 = (u16*)(ws + O_WSL12);
  u16* wslo  = (u16*)(ws + O_WSLO);
  u16* wxc   = (u16*)(ws + O_WXC);
  u16* wcc   = (u16*)(ws + O_WCC);
  u16* wca   = (u16*)(ws + O_WCA);
  uint2* precp = (uint2*)(ws + O_PREC);

  const dim3 B256(256);
  const dim3 TG(235, 1, 5);
  const int GPN = (P5 * NN + 255) / 256;
  const int GEN = (NE * NN + 255) / 256;
  constexpr int LDS_N128 = 65536;
  constexpr int LDS_N64  = 39936;
  constexpr int LDS_SLO  = 29952;
  constexpr int LDS_TGAT = 64 * RSA + 128 * RSA;   // 52224
  constexpr int LDS_FCA  = 64 * RSA * 2;           // 34816
  constexpr int LDS_CSR  = NN * 4;                 // 120000

  // ---- prep (element-parallel) ----
  temb_k<<<1, B256, 0, stream>>>(timesteps, te1_W, te1_b, te2_W, te2_b, tembp);
  embw_k<<<5, 128, 0, stream>>>(emb_W, emb_b, cemb_W, cemb_b, wcmb, bcmb);
  {
    auto WT = [&](const float* W, u16* Wt, int Kr, int Kp, int Nr, int Na, int B){
      int total = B * Na * Kp;
      wtransE_k<<<(total + 255) / 256, B256, 0, stream>>>(W, Wt, Kr, Kp, Nr, Na, total);
    };
    WT(pa_W, wpa, 128, 128, 128, 128, 5);
    WT(pc_W, wpc, 128, 128, 64, 64, 5);
    WT(sl0_W, wsl0, 69, 96, 128, 128, 5);
    WT(sl12_W, wsl12, 133, 160, 128, 128, 10);
    WT(slout_W, wslo, 133, 160, 13, 16, 5);
    WT(xc_W, wxc, 128, 128, 64, 64, 15);
    WT(cc_W, wcc, 128, 128, 64, 64, 15);
    WT(ca_W, wca, 128, 128, 128, 128, 15);
  }
  gwtT_k<<<(75 * 128 * 128 + 255) / 256, B256, 0, stream>>>(gat_W, gwt);
  gatred_k<<<75, 128, 0, stream>>>(gat_W, gat_as, gat_ad, gat_We, gat_ae, wswdp, eawp);

  // ---- segmented CSR build + gather-based eadot ----
  csr_cnt_k<<<NE * NSEG, 1024, LDS_CSR, stream>>>(edge_index, hseg);
  csr_b1_k<<<NE * 30, 1024, 0, stream>>>(hseg, ctot);
  csr_b2_k<<<NE, 64, 0, stream>>>(ctot, cbase, offs);
  csr_b3_k<<<NE * 30, 1024, 0, stream>>>(hseg, cbase, offs, bseg);
  csr_fill_k<<<NE * NSEG, 1024, LDS_CSR, stream>>>(edge_index, bseg, smp);
  eadot_k<<<(3 * NE * MM + 255) / 256, B256, 0, stream>>>(edge_attr, eawp, smp, eadotp);

  // ---- input embedding chain ----
  abuild_k<<<GPN, B256, 0, stream>>>(x, cond_x, A0);
  tgemm_k<8, 4, 4, 0, false><<<TG, B256, LDS_N128, stream>>>(A0, wcmb, bcmb, hcat, nullptr, 32, 128, 0, 0);
  tgemm_k<8, 4, 4, 1, false><<<TG, B256, LDS_N128, stream>>>(hcat, wpa, pa_b, hg, hcat, 128, 128, 0, 128);
  tgemm_k<4, 2, 4, 0, false><<<TG, B256, LDS_N64, stream>>>(hg, wpc, pc_b, h0buf, nullptr, 128, 96, 0, 0);
  ntfill_k<<<GPN, B256, 0, stream>>>(h0buf, 96, 64, batch_idx, tembp);

  // ---- layers ----
  for (int l = 0; l < 3; ++l){
    if (l == 0)
      tgemm_k<8, 4, 4, 2, false><<<TG, B256, LDS_N128, stream>>>(h0buf, wsl0, sl0_b, hS, nullptr, 96, 128, 0, 0);
    else
      tgemm_k<8, 4, 4, 2, false><<<TG, B256, LDS_N128, stream>>>(hL, wsl12 + (size_t)(l - 1) * 5 * 128 * 160,
                                                                 sl12_b + (size_t)(l - 1) * 5 * 128, hS, nullptr,
                                                                 160, 128, 0, 0);
    const float* wswd_l = wswdp + (size_t)l * 25 * 256;
    const u16* gwt_l = gwt + (size_t)l * 25 * 16384;
    const float* gb_l = gat_b + (size_t)l * 25 * 128;
    dots2_k<<<dim3(469, 5), B256, 0, stream>>>(hS, wswd_l, alsp, aldp);
    aexp_k<<<GEN, B256, 0, stream>>>(alsp, aldp, eadotp + (size_t)l * NE * MM, smp, offs, precp);
    for (int pd = 0; pd < 5; ++pd){
      agg3_k<<<dim3(3750, 5), B256, 0, stream>>>(hS, precp, offs, agghB, pd, 1);
      tgatmm_k<<<dim3(469), B256, LDS_TGAT, stream>>>(agghB, gwt_l, gb_l, comm, pd);
    }
    fca_k<<<dim3(469, 1, 5), B256, LDS_FCA, stream>>>(hS, comm,
        wxc + (size_t)l * 5 * 64 * 128, xc_b + (size_t)l * 5 * 64,
        wcc + (size_t)l * 5 * 64 * 128, cc_b + (size_t)l * 5 * 64,
        wca + (size_t)l * 5 * 128 * 128, ca_b + (size_t)l * 5 * 128,
        batch_idx, tembp, hL);
  }

  // ---- output head ----
  tgemm_k<1, 2, 1, 4, false><<<TG, B256, LDS_SLO, stream>>>(hL, wslo, slout_b, d_out, nullptr, 160, 13, 0, 0);
}